// Round 14
// baseline (1012.733 us; speedup 1.0000x reference)
//
#include <hip/hip_runtime.h>

typedef unsigned int u32;
typedef unsigned short u16;
typedef __attribute__((ext_vector_type(8))) short bf16x8;
typedef __attribute__((ext_vector_type(4))) float f32x4;

#define DEVI static __device__ __forceinline__

DEVI u16 f2bf(float f) {
    u32 u = __float_as_uint(f);
    u32 r = u + 0x7FFFu + ((u >> 16) & 1u);   // RNE (inputs finite)
    return (u16)(r >> 16);
}
DEVI float bf2f(u16 s) { return __uint_as_float(((u32)s) << 16); }
DEVI void split2(float a, u16& h, u16& l) {   // a ≈ hi + lo, residual ≤ 2^-18|a|
    h = f2bf(a);
    l = f2bf(a - bf2f(h));
}
DEVI int swz(int row) { return (row & 3) ^ ((row >> 2) & 3); }  // 32-col-tile swizzle key

// direct global->LDS DMA, 16 B/lane; LDS dest = wave-uniform base + lane*16
DEVI void gload16(const void* g, void* l) {
    __builtin_amdgcn_global_load_lds(
        (const __attribute__((address_space(1))) u32*)g,
        (__attribute__((address_space(3))) u32*)l, 16, 0, 0);
}

union U4 { uint4 v; u16 s[8]; };

// ---------------------------------------------------------------- f32 -> (hi,lo) bf16 planes
__global__ __launch_bounds__(256) void convert_split_kernel(const float* __restrict__ in,
                                                            u16* __restrict__ hi,
                                                            u16* __restrict__ lo, int n) {
    int i = blockIdx.x * 256 + threadIdx.x;
    if (i < n) { u16 h, l; split2(in[i], h, l); hi[i] = h; lo[i] = l; }
}

// ---------------------------------------------------------------- proxy-side K/V (tiny, fp32 VALU)
struct KVArgs {
    const float *proxy;
    const float *ow1, *og1, *ob1, *om1, *ov1;
    const float *ow2, *og2, *ob2, *om2, *ov2;
    const float *dw,  *dg,  *db,  *dm,  *dv;
    float *kmat;   // [B][256][19]
    float *vmat;   // [B][19][256]
};
__global__ __launch_bounds__(256) void kv_kernel(KVArgs a) {
    __shared__ float pl[512 * 19];
    __shared__ float t1[256 * 19];
    const int t = threadIdx.x;
    const int b = blockIdx.x;
    const float* pb = a.proxy + (size_t)b * 512 * 19;
    for (int i = t; i < 512 * 19; i += 256) pl[i] = pb[i];
    __syncthreads();
    const int o = t;
    {
        float acc[19] = {0.f};
        const float* wr = a.ow1 + (size_t)o * 512;
        for (int c = 0; c < 512; ++c) {
            float wv = wr[c];
#pragma unroll
            for (int kk = 0; kk < 19; ++kk) acc[kk] += wv * pl[c * 19 + kk];
        }
        float sc = a.og1[o] * __frsqrt_rn(a.ov1[o] + 1e-5f);
        float sh = a.ob1[o] - a.om1[o] * sc;
#pragma unroll
        for (int kk = 0; kk < 19; ++kk) t1[o * 19 + kk] = fmaxf(acc[kk] * sc + sh, 0.f);
    }
    __syncthreads();
    {
        float acc[19] = {0.f};
        const float* wr = a.ow2 + (size_t)o * 256;
        for (int c = 0; c < 256; ++c) {
            float wv = wr[c];
#pragma unroll
            for (int kk = 0; kk < 19; ++kk) acc[kk] += wv * t1[c * 19 + kk];
        }
        float sc = a.og2[o] * __frsqrt_rn(a.ov2[o] + 1e-5f);
        float sh = a.ob2[o] - a.om2[o] * sc;
#pragma unroll
        for (int kk = 0; kk < 19; ++kk)
            a.kmat[((size_t)b * 256 + o) * 19 + kk] = fmaxf(acc[kk] * sc + sh, 0.f);
    }
    {
        float acc[19] = {0.f};
        const float* wr = a.dw + (size_t)o * 512;
        for (int c = 0; c < 512; ++c) {
            float wv = wr[c];
#pragma unroll
            for (int kk = 0; kk < 19; ++kk) acc[kk] += wv * pl[c * 19 + kk];
        }
        float sc = a.dg[o] * __frsqrt_rn(a.dv[o] + 1e-5f);
        float sh = a.db[o] - a.dm[o] * sc;
#pragma unroll
        for (int kk = 0; kk < 19; ++kk)
            a.vmat[((size_t)b * 19 + kk) * 256 + o] = fmaxf(acc[kk] * sc + sh, 0.f);
    }
}

// ---------------------------------------------------------------- attention (fp32 q rows)
struct AttnArgs { const float* q2f; const float* kmat; const float* vmat;
                  u16* ctxh; u16* ctxl; long long p_off; };
__global__ __launch_bounds__(256) void attn_kernel(AttnArgs a) {
    __shared__ float kl[4864];   // [c][19]
    __shared__ float vl[4864];   // [kk][256]
    const int t = threadIdx.x;
    const size_t pl_ = (size_t)blockIdx.x * 256;          // pass-local pixel base
    const size_t pg  = (size_t)a.p_off + pl_;             // global pixel base
    const int b = (int)(pg >> 14);
    for (int i = t; i < 4864; i += 256) { kl[i] = a.kmat[(size_t)b * 4864 + i];
                                          vl[i] = a.vmat[(size_t)b * 4864 + i]; }
    __syncthreads();
    const float* qrow = a.q2f + (pl_ + t) * 256;          // pass-local fp32 row, 1 KB
    float sim[19];
#pragma unroll
    for (int kk = 0; kk < 19; ++kk) sim[kk] = 0.f;
    for (int j = 0; j < 64; ++j) {
        float4 qv = reinterpret_cast<const float4*>(qrow)[j];
#pragma unroll
        for (int e = 0; e < 4; ++e) {
            float qf = (e == 0) ? qv.x : (e == 1) ? qv.y : (e == 2) ? qv.z : qv.w;
            int c = j * 4 + e;
#pragma unroll
            for (int kk = 0; kk < 19; ++kk) sim[kk] += qf * kl[c * 19 + kk];
        }
    }
    float mx = -1e30f;
#pragma unroll
    for (int kk = 0; kk < 19; ++kk) { sim[kk] *= 0.0625f; mx = fmaxf(mx, sim[kk]); }
    float ssum = 0.f;
#pragma unroll
    for (int kk = 0; kk < 19; ++kk) { sim[kk] = __expf(sim[kk] - mx); ssum += sim[kk]; }
    const float inv = 1.f / ssum;
#pragma unroll
    for (int kk = 0; kk < 19; ++kk) sim[kk] *= inv;
    u16* crh = a.ctxh + (pg + t) * 256;
    u16* crl = a.ctxl + (pg + t) * 256;
    for (int j = 0; j < 32; ++j) {
        U4 hh, ll;
#pragma unroll
        for (int e = 0; e < 8; ++e) {
            int c = j * 8 + e;
            float acc = 0.f;
#pragma unroll
            for (int kk = 0; kk < 19; ++kk) acc += sim[kk] * vl[kk * 256 + c];
            split2(acc, hh.s[e], ll.s[e]);
        }
        *reinterpret_cast<uint4*>(crh + j * 8) = hh.v;
        *reinterpret_cast<uint4*>(crl + j * 8) = ll.v;
    }
}

// ---------------------------------------------------------------- FUSED gemm1+gemm2, 64-px blocks, 3 blocks/CU
// Phase 1: xs reg-staged dbuf (16 KB) + W1 SINGLE-buffer DMA (32 KB) -> 48 KB LDS total.
//   2 barriers/step (barA: reads done -> DMA overwrite; barB: DMA drained). Static fxA/fxB
//   x prefetch (2x-unrolled step pairs, rule #20 safe). TLP (12 waves/CU) covers drains.
// Phase 2: W2 direct-from-global (L2-hot); q1 LDS 280-u16 rows; s2 loop barrier-free.
struct F12Args {
    const float* Xf;
    const u16 *W1h, *W1l, *W2h, *W2l;
    const float *g1, *b1, *m1, *v1;
    const float *g2, *b2, *m2, *v2;
    float* q2f;     // pass-local [chunk_px][256] fp32
    int m_off;
};
__global__ __launch_bounds__(256, 3) void fused12_kernel(F12Args a) {
    __shared__ char LB[49152];
    u16* xs = (u16*)LB;               // 2 buf x 2 planes x [64][32] u16  (16384 B)
    u16* wb = (u16*)(LB + 16384);     // 1 buf x 2 planes x [256][32] u16 (32768 B)
    u16* q1 = (u16*)LB;               // phase2: 2 planes x 16 rows x 280 u16 (17920 B; xs+wb dead)
    float* tf = (float*)LB;           // epilogue: [16][260] f32 (16640 B), aliases q1

    const int t = threadIdx.x;
    const int l = t & 63, w = t >> 6;
    const int wr = w >> 1, wc = w & 1;
    const int l15 = l & 15, l4 = l >> 4;
    const int mloc = blockIdx.x * 64;
    const int mg = a.m_off + mloc;
    const int bb = mg >> 14, nb = mg & 16383;   // 64 | 16384 -> no batch straddle

    f32x4 acc1[2][8];
#pragma unroll
    for (int mi = 0; mi < 2; ++mi)
#pragma unroll
        for (int ni = 0; ni < 8; ++ni) acc1[mi][ni] = f32x4{0.f, 0.f, 0.f, 0.f};

    float fxA[8], fxB[8];             // static x prefetch buffers

    // per-lane DMA source precompute (lane-only swizzle: 16-row groups)
    const int dsw = ((l & 3) ^ ((l >> 2) & 3) ^ ((l >> 4) & 3)) * 8;  // source col offset (u16)
    const int drow = l >> 2;                                           // row within 16-row group

    auto loadXi = [&](int s, float (&fx)[8]) {
        const int px = t & 63, oct = t >> 6;     // 256 tasks: 64 px x 4 octs
        const float* src = a.Xf + (((size_t)bb * 512 + s * 32 + oct * 8) << 14) + nb + px;
#pragma unroll
        for (int e = 0; e < 8; ++e) fx[e] = src[(size_t)e << 14];
    };
    auto writeXi = [&](float (&fx)[8], int buf) {
        const int px = t & 63, oct = t >> 6;
        U4 ph, plo;
#pragma unroll
        for (int e = 0; e < 8; ++e) split2(fx[e], ph.s[e], plo.s[e]);
        int pos = buf * 4096 + px * 32 + ((oct ^ swz(px)) * 8);
        *reinterpret_cast<uint4*>(&xs[pos]) = ph.v;
        *reinterpret_cast<uint4*>(&xs[2048 + pos]) = plo.v;
    };
    auto dmaW1 = [&](int s) {
        // wave w stages rows [w*64, w*64+64), both planes: 8 gload16 (16 rows each)
#pragma unroll
        for (int i = 0; i < 8; ++i) {
            const int p = i >> 2, g = i & 3;
            const int row16 = w * 64 + g * 16;
            const u16* src = (p ? a.W1l : a.W1h) + (size_t)(row16 + drow) * 512 + s * 32 + dsw;
            gload16(src, &wb[p * 8192 + row16 * 32]);
        }
    };
    auto mfmaStep = [&](int p) {       // p = xs buffer parity (compile-time at call sites)
        bf16x8 ah[2], am[2];
#pragma unroll
        for (int mi = 0; mi < 2; ++mi) {
            int ar = wr * 32 + mi * 16 + l15;
            int ap = p * 4096 + ar * 32 + ((l4 ^ swz(ar)) * 8);
            ah[mi] = *reinterpret_cast<const bf16x8*>(&xs[ap]);
            am[mi] = *reinterpret_cast<const bf16x8*>(&xs[2048 + ap]);
        }
#pragma unroll
        for (int ni = 0; ni < 8; ++ni) {
            int br = wc * 128 + ni * 16 + l15;
            int bp = br * 32 + ((l4 ^ swz(br)) * 8);
            bf16x8 bh = *reinterpret_cast<const bf16x8*>(&wb[bp]);
            bf16x8 bl_ = *reinterpret_cast<const bf16x8*>(&wb[8192 + bp]);
#pragma unroll
            for (int mi = 0; mi < 2; ++mi) {
                acc1[mi][ni] = __builtin_amdgcn_mfma_f32_16x16x32_bf16(ah[mi], bh, acc1[mi][ni], 0, 0, 0);
                acc1[mi][ni] = __builtin_amdgcn_mfma_f32_16x16x32_bf16(ah[mi], bl_, acc1[mi][ni], 0, 0, 0);
                acc1[mi][ni] = __builtin_amdgcn_mfma_f32_16x16x32_bf16(am[mi], bh, acc1[mi][ni], 0, 0, 0);
            }
        }
    };

    // ---------------- phase 1: K=512 in 16 steps of 32 (2x-unrolled step pairs)
    loadXi(0, fxA);
    dmaW1(0);
    writeXi(fxA, 0);
    loadXi(1, fxB);
    __syncthreads();                             // drains DMA(0) + x loads + xs writes
#pragma unroll 1
    for (int si = 0; si < 8; ++si) {
        const int s = si * 2;
        // even step s: compute xs[0] x wb(s)
        mfmaStep(0);
        writeXi(fxB, 1);                         // x(s+1) -> xs[1]  (s<=14 so always valid)
        __syncthreads();                         // barA: wb reads + xs[1] writes done
        if (s < 14) loadXi(s + 2, fxA);
        if (s < 15) dmaW1(s + 1);                // overwrite wb with W1(s+1)
        __syncthreads();                         // barB: DMA + x loads drained
        // odd step s+1: compute xs[1] x wb(s+1)
        mfmaStep(1);
        if (s + 1 < 15) writeXi(fxA, 0);         // x(s+2) -> xs[0]
        __syncthreads();                         // barA
        if (s + 1 < 14) loadXi(s + 3, fxB);
        if (s + 1 < 15) dmaW1(s + 2);
        __syncthreads();                         // barB
    }

    // BN coefficients
    float scl1[8], shf1[8];
#pragma unroll
    for (int ni = 0; ni < 8; ++ni) {
        int o = wc * 128 + ni * 16 + l15;
        scl1[ni] = a.g1[o] * __frsqrt_rn(a.v1[o] + 1e-5f);
        shf1[ni] = a.b1[o] - a.m1[o] * scl1[ni];
    }
    float scl2[4], shf2[4];
#pragma unroll
    for (int ni = 0; ni < 4; ++ni) {
        int o = w * 64 + ni * 16 + l15;
        scl2[ni] = a.g2[o] * __frsqrt_rn(a.v2[o] + 1e-5f);
        shf2[ni] = a.b2[o] - a.m2[o] * scl2[ni];
    }

    // ---------------- phase 2: 4 chunks of 16 px; W2 direct-from-global (L2-hot)
#pragma unroll
    for (int pxq = 0; pxq < 4; ++pxq) {
        const int mi = pxq & 1;                // compile-time (full unroll)
        __syncthreads();                       // prior LDS users (phase1 / tf readers) done
        if (wr == (pxq >> 1)) {                // owning px-half; both wc waves write their o-half
#pragma unroll
            for (int ni = 0; ni < 8; ++ni) {
                int o1 = wc * 128 + ni * 16 + l15;
                int base = (o1 >> 3) * 8 + (o1 & 7);
#pragma unroll
                for (int r = 0; r < 4; ++r) {
                    int px_l = l4 * 4 + r;     // 0..15 within chunk
                    float y = fmaxf(acc1[mi][ni][r] * scl1[ni] + shf1[ni], 0.f);
                    u16 h, lo; split2(y, h, lo);
                    int pos = px_l * 280 + base;
                    q1[pos] = h;
                    q1[4480 + pos] = lo;       // lo plane at +8960 B
                }
            }
        }
        __syncthreads();                       // q1 visible to all waves

        f32x4 acc2[4];
#pragma unroll
        for (int ni = 0; ni < 4; ++ni) acc2[ni] = f32x4{0.f, 0.f, 0.f, 0.f};

#pragma unroll
        for (int s2 = 0; s2 < 8; ++s2) {       // K2=256, barrier-free: q1 read-only, W2 from global
            int ap = l15 * 280 + (s2 * 4 + l4) * 8;
            bf16x8 a2h = *reinterpret_cast<const bf16x8*>(&q1[ap]);
            bf16x8 a2m = *reinterpret_cast<const bf16x8*>(&q1[4480 + ap]);
#pragma unroll
            for (int ni = 0; ni < 4; ++ni) {
                size_t boff = (size_t)(w * 64 + ni * 16 + l15) * 256 + s2 * 32 + l4 * 8;
                bf16x8 b2h = *reinterpret_cast<const bf16x8*>(&a.W2h[boff]);
                bf16x8 b2l = *reinterpret_cast<const bf16x8*>(&a.W2l[boff]);
                acc2[ni] = __builtin_amdgcn_mfma_f32_16x16x32_bf16(a2h, b2h, acc2[ni], 0, 0, 0);
                acc2[ni] = __builtin_amdgcn_mfma_f32_16x16x32_bf16(a2h, b2l, acc2[ni], 0, 0, 0);
                acc2[ni] = __builtin_amdgcn_mfma_f32_16x16x32_bf16(a2m, b2h, acc2[ni], 0, 0, 0);
            }
        }
        __syncthreads();                       // all q1 reads done before tf overwrites (alias)

        // epilogue: BN2+ReLU -> tf [16][260] f32 -> coalesced float4 stores
#pragma unroll
        for (int ni = 0; ni < 4; ++ni) {
            int o2 = w * 64 + ni * 16 + l15;
#pragma unroll
            for (int r = 0; r < 4; ++r) {
                int px_l = l4 * 4 + r;
                tf[px_l * 260 + o2] = fmaxf(acc2[ni][r] * scl2[ni] + shf2[ni], 0.f);
            }
        }
        __syncthreads();
#pragma unroll
        for (int j = 0; j < 4; ++j) {          // 16 rows x 256 f32
            int task = j * 256 + t;
            int row = task >> 6, c4 = task & 63;
            *reinterpret_cast<float4*>(&a.q2f[(size_t)(mloc + pxq * 16 + row) * 256 + c4 * 4]) =
                *reinterpret_cast<const float4*>(&tf[row * 260 + c4 * 4]);
        }
    }
}

// ---------------------------------------------------------------- gemm_up: ctx(split planes) -> out[b][o][n] fp32
// NO main-loop LDS, NO barriers (validated R13): fragments direct from global/L2.
struct GUArgs {
    const u16 *Ah, *Al, *Wh, *Wl;
    const float *gg, *bbv, *mmv, *vvv;
    float* Yf;
};
__global__ __launch_bounds__(256, 2) void gemm_up_kernel(GUArgs a) {
    __shared__ float ldsf[128 * 68];          // epilogue only (34816 B)
    const int t = threadIdx.x;
    const int l = t & 63;
    const int w = t >> 6;
    const int wr = w >> 1, wc = w & 1;
    const int l15 = l & 15, l4 = l >> 4;
    const int id = blockIdx.y * 4 + blockIdx.x;
    const int wid = (id & 7) * 1024 + (id >> 3);  // bijective XCD chunking (nwg=8192)
    const int o0 = (wid & 3) * 128;
    const int m  = (wid >> 2) * 64;
    const int bb = m >> 14;                   // 64 | 16384 -> no batch straddle
    const int nb = m & 16383;

    f32x4 acc[2][4];
#pragma unroll
    for (int mi = 0; mi < 2; ++mi)
#pragma unroll
        for (int ni = 0; ni < 4; ++ni) acc[mi][ni] = f32x4{0.f, 0.f, 0.f, 0.f};

    // per-lane fragment base offsets (k-octet l4 baked in)
    size_t abase[2], wbase[4];
#pragma unroll
    for (int mi = 0; mi < 2; ++mi)
        abase[mi] = (size_t)(m + wr * 32 + mi * 16 + l15) * 256 + l4 * 8;
#pragma unroll
    for (int ni = 0; ni < 4; ++ni)
        wbase[ni] = (size_t)(o0 + wc * 64 + ni * 16 + l15) * 256 + l4 * 8;

#pragma unroll 2
    for (int s = 0; s < 8; ++s) {             // K=256 in 8 steps of 32, barrier-free
        const int ko = s * 32;
        bf16x8 ah[2], al[2], bh[4], bl[4];
#pragma unroll
        for (int mi = 0; mi < 2; ++mi) {
            ah[mi] = *reinterpret_cast<const bf16x8*>(a.Ah + abase[mi] + ko);
            al[mi] = *reinterpret_cast<const bf16x8*>(a.Al + abase[mi] + ko);
        }
#pragma unroll
        for (int ni = 0; ni < 4; ++ni) {
            bh[ni] = *reinterpret_cast<const bf16x8*>(a.Wh + wbase[ni] + ko);
            bl[ni] = *reinterpret_cast<const bf16x8*>(a.Wl + wbase[ni] + ko);
        }
#pragma unroll
        for (int mi = 0; mi < 2; ++mi)
#pragma unroll
            for (int ni = 0; ni < 4; ++ni) {
                acc[mi][ni] = __builtin_amdgcn_mfma_f32_16x16x32_bf16(ah[mi], bh[ni], acc[mi][ni], 0, 0, 0);
                acc[mi][ni] = __builtin_amdgcn_mfma_f32_16x16x32_bf16(ah[mi], bl[ni], acc[mi][ni], 0, 0, 0);
                acc[mi][ni] = __builtin_amdgcn_mfma_f32_16x16x32_bf16(al[mi], bh[ni], acc[mi][ni], 0, 0, 0);
            }
    }

    float scl[4], shf[4];
#pragma unroll
    for (int ni = 0; ni < 4; ++ni) {
        int o = o0 + wc * 64 + ni * 16 + l15;
        scl[ni] = a.gg[o] * __frsqrt_rn(a.vvv[o] + 1e-5f);
        shf[ni] = a.bbv[o] - a.mmv[o] * scl[ni];
    }

    // epilogue: transpose via LDS [128 o][68 n] f32 -> out[b][o][16384] coalesced
#pragma unroll
    for (int ni = 0; ni < 4; ++ni) {
        int o_l = wc * 64 + ni * 16 + l15;
#pragma unroll
        for (int mi = 0; mi < 2; ++mi)
#pragma unroll
            for (int r = 0; r < 4; ++r) {
                int n_l = wr * 32 + mi * 16 + l4 * 4 + r;
                float y = fmaxf(acc[mi][ni][r] * scl[ni] + shf[ni], 0.f);
                ldsf[o_l * 68 + n_l] = y;
            }
    }
    __syncthreads();
#pragma unroll
    for (int j = 0; j < 8; ++j) {             // 128 rows x 16 float4
        int idx = j * 256 + t;
        int row = idx >> 4, c4 = (idx & 15) * 4;
        *reinterpret_cast<float4*>(&a.Yf[((size_t)bb << 23) + (size_t)(o0 + row) * 16384 + nb + c4]) =
            *reinterpret_cast<const float4*>(&ldsf[row * 68 + c4]);
    }
}

// ---------------------------------------------------------------- launch
extern "C" void kernel_launch(void* const* d_in, const int* in_sizes, int n_in,
                              void* d_out, int out_size, void* d_ws, size_t ws_size,
                              hipStream_t stream) {
    const float* x     = (const float*)d_in[0];
    const float* proxy = (const float*)d_in[1];
    const float* pw1 = (const float*)d_in[2];
    const float* pg1 = (const float*)d_in[3];
    const float* pb1 = (const float*)d_in[4];
    const float* pm1 = (const float*)d_in[5];
    const float* pv1 = (const float*)d_in[6];
    const float* pw2 = (const float*)d_in[7];
    const float* pg2 = (const float*)d_in[8];
    const float* pb2 = (const float*)d_in[9];
    const float* pm2 = (const float*)d_in[10];
    const float* pv2 = (const float*)d_in[11];
    const float* ow1 = (const float*)d_in[12];
    const float* og1 = (const float*)d_in[13];
    const float* ob1 = (const float*)d_in[14];
    const float* om1 = (const float*)d_in[15];
    const float* ov1 = (const float*)d_in[16];
    const float* ow2 = (const float*)d_in[17];
    const float* og2 = (const float*)d_in[18];
    const float* ob2 = (const float*)d_in[19];
    const float* om2 = (const float*)d_in[20];
    const float* ov2 = (const float*)d_in[21];
    const float* dw  = (const float*)d_in[22];
    const float* dg  = (const float*)d_in[23];
    const float* db  = (const float*)d_in[24];
    const float* dm  = (const float*)d_in[25];
    const float* dv  = (const float*)d_in[26];
    const float* uw  = (const float*)d_in[27];
    const float* ug  = (const float*)d_in[28];
    const float* ub  = (const float*)d_in[29];
    const float* um  = (const float*)d_in[30];
    const float* uv  = (const float*)d_in[31];

    char* ws = (char*)d_ws;
    u16* wpw1h = (u16*)(ws + 0);                 // 262144 B
    u16* wpw1l = (u16*)(ws + 262144);
    u16* wpw2h = (u16*)(ws + 524288);            // 131072 B
    u16* wpw2l = (u16*)(ws + 655360);
    u16* wuwh  = (u16*)(ws + 786432);            // 262144 B
    u16* wuwl  = (u16*)(ws + 1048576);
    float* kmat = (float*)(ws + 1310720);        // 155648 B
    float* vmat = (float*)(ws + 1466368);        // 155648 B -> ends 1622016
    u16* ctxh = (u16*)(ws + 2097152);            // 67108864 B
    u16* ctxl = (u16*)(ws + 69206016);           // 67108864 B -> ends 136314880
    float* q2f = (float*)(ws + 136314880ull);    // 134217728/passes B, [chunk][256] fp32

    int passes = 1;
    while (passes < 16 && 136314880ull + 134217728ull / (size_t)passes > ws_size) passes <<= 1;

    convert_split_kernel<<<512, 256, 0, stream>>>(pw1, wpw1h, wpw1l, 131072);
    convert_split_kernel<<<256, 256, 0, stream>>>(pw2, wpw2h, wpw2l, 65536);
    convert_split_kernel<<<512, 256, 0, stream>>>(uw,  wuwh,  wuwl,  131072);

    KVArgs ka{proxy, ow1, og1, ob1, om1, ov1, ow2, og2, ob2, om2, ov2,
              dw, dg, db, dm, dv, kmat, vmat};
    kv_kernel<<<8, 256, 0, stream>>>(ka);

    const int mpix = 131072 / passes;            // pixels per pass
    for (int p = 0; p < passes; ++p) {
        const int m_off = p * mpix;
        F12Args fa{x, wpw1h, wpw1l, wpw2h, wpw2l,
                   pg1, pb1, pm1, pv1, pg2, pb2, pm2, pv2, q2f, m_off};
        fused12_kernel<<<mpix / 64, 256, 0, stream>>>(fa);
        AttnArgs aa{q2f, kmat, vmat, ctxh, ctxl, (long long)m_off};
        attn_kernel<<<mpix / 256, 256, 0, stream>>>(aa);
    }

    // gemm_up: ctx -> out[b][o][n] fp32, K=256, COUT=512, 64x128 tiles
    GUArgs ga{ctxh, ctxl, wuwh, wuwl, ug, ub, um, uv, (float*)d_out};
    gemm_up_kernel<<<dim3(4, 2048), 256, 0, stream>>>(ga);
}

// Round 15
// 1002.800 us; speedup vs baseline: 1.0099x; 1.0099x over previous
//
#include <hip/hip_runtime.h>

typedef unsigned int u32;
typedef unsigned short u16;
typedef __attribute__((ext_vector_type(8))) short bf16x8;
typedef __attribute__((ext_vector_type(4))) float f32x4;

#define DEVI static __device__ __forceinline__

DEVI u16 f2bf(float f) {
    u32 u = __float_as_uint(f);
    u32 r = u + 0x7FFFu + ((u >> 16) & 1u);   // RNE (inputs finite)
    return (u16)(r >> 16);
}
DEVI float bf2f(u16 s) { return __uint_as_float(((u32)s) << 16); }
DEVI void split2(float a, u16& h, u16& l) {   // a ≈ hi + lo, residual ≤ 2^-18|a|
    h = f2bf(a);
    l = f2bf(a - bf2f(h));
}
DEVI int swz(int row) { return (row & 3) ^ ((row >> 2) & 3); }  // 32-col-tile swizzle key

// direct global->LDS DMA, 16 B/lane; LDS dest = wave-uniform base + lane*16
DEVI void gload16(const void* g, void* l) {
    __builtin_amdgcn_global_load_lds(
        (const __attribute__((address_space(1))) u32*)g,
        (__attribute__((address_space(3))) u32*)l, 16, 0, 0);
}

union U4 { uint4 v; u16 s[8]; };

// ---------------------------------------------------------------- f32 -> (hi,lo) bf16 planes
__global__ __launch_bounds__(256) void convert_split_kernel(const float* __restrict__ in,
                                                            u16* __restrict__ hi,
                                                            u16* __restrict__ lo, int n) {
    int i = blockIdx.x * 256 + threadIdx.x;
    if (i < n) { u16 h, l; split2(in[i], h, l); hi[i] = h; lo[i] = l; }
}

// ---------------------------------------------------------------- proxy-side K/V (tiny, fp32 VALU)
struct KVArgs {
    const float *proxy;
    const float *ow1, *og1, *ob1, *om1, *ov1;
    const float *ow2, *og2, *ob2, *om2, *ov2;
    const float *dw,  *dg,  *db,  *dm,  *dv;
    float *kmat;   // [B][256][19]
    float *vmat;   // [B][19][256]
};
__global__ __launch_bounds__(256) void kv_kernel(KVArgs a) {
    __shared__ float pl[512 * 19];
    __shared__ float t1[256 * 19];
    const int t = threadIdx.x;
    const int b = blockIdx.x;
    const float* pb = a.proxy + (size_t)b * 512 * 19;
    for (int i = t; i < 512 * 19; i += 256) pl[i] = pb[i];
    __syncthreads();
    const int o = t;
    {
        float acc[19] = {0.f};
        const float* wr = a.ow1 + (size_t)o * 512;
        for (int c = 0; c < 512; ++c) {
            float wv = wr[c];
#pragma unroll
            for (int kk = 0; kk < 19; ++kk) acc[kk] += wv * pl[c * 19 + kk];
        }
        float sc = a.og1[o] * __frsqrt_rn(a.ov1[o] + 1e-5f);
        float sh = a.ob1[o] - a.om1[o] * sc;
#pragma unroll
        for (int kk = 0; kk < 19; ++kk) t1[o * 19 + kk] = fmaxf(acc[kk] * sc + sh, 0.f);
    }
    __syncthreads();
    {
        float acc[19] = {0.f};
        const float* wr = a.ow2 + (size_t)o * 256;
        for (int c = 0; c < 256; ++c) {
            float wv = wr[c];
#pragma unroll
            for (int kk = 0; kk < 19; ++kk) acc[kk] += wv * t1[c * 19 + kk];
        }
        float sc = a.og2[o] * __frsqrt_rn(a.ov2[o] + 1e-5f);
        float sh = a.ob2[o] - a.om2[o] * sc;
#pragma unroll
        for (int kk = 0; kk < 19; ++kk)
            a.kmat[((size_t)b * 256 + o) * 19 + kk] = fmaxf(acc[kk] * sc + sh, 0.f);
    }
    {
        float acc[19] = {0.f};
        const float* wr = a.dw + (size_t)o * 512;
        for (int c = 0; c < 512; ++c) {
            float wv = wr[c];
#pragma unroll
            for (int kk = 0; kk < 19; ++kk) acc[kk] += wv * pl[c * 19 + kk];
        }
        float sc = a.dg[o] * __frsqrt_rn(a.dv[o] + 1e-5f);
        float sh = a.db[o] - a.dm[o] * sc;
#pragma unroll
        for (int kk = 0; kk < 19; ++kk)
            a.vmat[((size_t)b * 19 + kk) * 256 + o] = fmaxf(acc[kk] * sc + sh, 0.f);
    }
}

// ---------------------------------------------------------------- FUSED gemm1+gemm2+ATTENTION, 64-px blocks, 2 blocks/CU
// Phase 1 (benched R13 structure): xs dbuf 16 KB + wb dbuf 64 KB, 1 barrier/step.
// Phase 2 per 16-px chunk: q1->LDS, gemm2 (W2 direct-from-global), q2->tf fp32,
//   then ATTENTION in-block (sim partials -> softmax -> ctx) -> coalesced ctx stores.
// K/V (39 KB) loaded once into dead wb region after phase 1.
struct F12Args {
    const float* Xf;
    const u16 *W1h, *W1l, *W2h, *W2l;
    const float *g1, *b1, *m1, *v1;
    const float *g2, *b2, *m2, *v2;
    const float *kmat, *vmat;
    u16 *ctxh, *ctxl;
};
__global__ __launch_bounds__(256, 2) void fused12_kernel(F12Args a) {
    __shared__ char LB[81920];
    u16* xs = (u16*)LB;                 // phase1: 2 buf x 2 planes x [64][32] u16  (16384 B)
    u16* wb = (u16*)(LB + 16384);       // phase1: 2 buf x 2 planes x [256][32] u16 (65536 B)
    u16* q1 = (u16*)LB;                 // phase2: 2 planes x 16 rows x 280 u16 [0, 17920)
    float* tf = (float*)LB;             // q2 tile [16][260] f32 [0, 16640), aliases q1
    u16* ch = (u16*)LB;                 // ctx hi staging [16][264] u16 [0, 8448)
    u16* cl = (u16*)(LB + 8448);        // ctx lo staging [8448, 16896)
    float* kl = (float*)(LB + 18432);   // K [256][19] f32 [18432, 37888)
    float* vl = (float*)(LB + 37888);   // V [19][256] f32 [37888, 57344)
    float* sp = (float*)(LB + 57344);   // sim partials [16 cg][16 px][20] f32 [57344, 77824)

    const int t = threadIdx.x;
    const int l = t & 63, w = t >> 6;
    const int wr = w >> 1, wc = w & 1;
    const int l15 = l & 15, l4 = l >> 4;
    const int mg = blockIdx.x * 64;
    const int bb = mg >> 14, nb = mg & 16383;   // 64 | 16384 -> no batch straddle

    f32x4 acc1[2][8];
#pragma unroll
    for (int mi = 0; mi < 2; ++mi)
#pragma unroll
        for (int ni = 0; ni < 8; ++ni) acc1[mi][ni] = f32x4{0.f, 0.f, 0.f, 0.f};

    float fx[8];

    // per-lane DMA source precompute (lane-only swizzle: 16-row groups)
    const int dsw = ((l & 3) ^ ((l >> 2) & 3) ^ ((l >> 4) & 3)) * 8;  // source col offset (u16)
    const int drow = l >> 2;                                           // row within 16-row group

    auto loadX = [&](int s) {
        const int px = t & 63, oct = t >> 6;     // 256 tasks: 64 px x 4 octs
        const float* src = a.Xf + (((size_t)bb * 512 + s * 32 + oct * 8) << 14) + nb + px;
#pragma unroll
        for (int e = 0; e < 8; ++e) fx[e] = src[(size_t)e << 14];
    };
    auto writeX = [&](int buf) {
        const int px = t & 63, oct = t >> 6;
        U4 ph, plo;
#pragma unroll
        for (int e = 0; e < 8; ++e) split2(fx[e], ph.s[e], plo.s[e]);
        int pos = buf * 4096 + px * 32 + ((oct ^ swz(px)) * 8);
        *reinterpret_cast<uint4*>(&xs[pos]) = ph.v;
        *reinterpret_cast<uint4*>(&xs[2048 + pos]) = plo.v;
    };
    auto dmaW1 = [&](int s, int buf) {
#pragma unroll
        for (int i = 0; i < 8; ++i) {
            const int p = i >> 2, g = i & 3;
            const int row16 = w * 64 + g * 16;
            const u16* src = (p ? a.W1l : a.W1h) + (size_t)(row16 + drow) * 512 + s * 32 + dsw;
            u16* dst = &wb[buf * 16384 + p * 8192 + row16 * 32];
            gload16(src, dst);
        }
    };

    // ---------------- phase 1: K=512 in 16 steps of 32, single barrier/step (R13 structure)
    loadX(0); dmaW1(0, 0);
    writeX(0);
    loadX(1);
    __syncthreads();
    int cur = 0;
    for (int s = 0; s < 16; ++s) {
        if (s < 15) dmaW1(s + 1, cur ^ 1);
        bf16x8 ah[2], am[2];
#pragma unroll
        for (int mi = 0; mi < 2; ++mi) {
            int ar = wr * 32 + mi * 16 + l15;
            int ap = cur * 4096 + ar * 32 + ((l4 ^ swz(ar)) * 8);
            ah[mi] = *reinterpret_cast<const bf16x8*>(&xs[ap]);
            am[mi] = *reinterpret_cast<const bf16x8*>(&xs[2048 + ap]);
        }
#pragma unroll
        for (int ni = 0; ni < 8; ++ni) {
            int br = wc * 128 + ni * 16 + l15;
            int bp = cur * 16384 + br * 32 + ((l4 ^ swz(br)) * 8);
            bf16x8 bh = *reinterpret_cast<const bf16x8*>(&wb[bp]);
            bf16x8 bl_ = *reinterpret_cast<const bf16x8*>(&wb[8192 + bp]);
#pragma unroll
            for (int mi = 0; mi < 2; ++mi) {
                acc1[mi][ni] = __builtin_amdgcn_mfma_f32_16x16x32_bf16(ah[mi], bh, acc1[mi][ni], 0, 0, 0);
                acc1[mi][ni] = __builtin_amdgcn_mfma_f32_16x16x32_bf16(ah[mi], bl_, acc1[mi][ni], 0, 0, 0);
                acc1[mi][ni] = __builtin_amdgcn_mfma_f32_16x16x32_bf16(am[mi], bh, acc1[mi][ni], 0, 0, 0);
            }
        }
        if (s < 15) {
            writeX(cur ^ 1);
            if (s < 14) loadX(s + 2);
        }
        __syncthreads();
        cur ^= 1;
    }

    // load K/V for this batch into dead wb region
    {
        const float* kb = a.kmat + (size_t)bb * 4864;
        const float* vb = a.vmat + (size_t)bb * 4864;
        for (int i = t; i < 4864; i += 256) { kl[i] = kb[i]; vl[i] = vb[i]; }
    }
    __syncthreads();

    // BN coefficients
    float scl1[8], shf1[8];
#pragma unroll
    for (int ni = 0; ni < 8; ++ni) {
        int o = wc * 128 + ni * 16 + l15;
        scl1[ni] = a.g1[o] * __frsqrt_rn(a.v1[o] + 1e-5f);
        shf1[ni] = a.b1[o] - a.m1[o] * scl1[ni];
    }
    float scl2[4], shf2[4];
#pragma unroll
    for (int ni = 0; ni < 4; ++ni) {
        int o = w * 64 + ni * 16 + l15;
        scl2[ni] = a.g2[o] * __frsqrt_rn(a.v2[o] + 1e-5f);
        shf2[ni] = a.b2[o] - a.m2[o] * scl2[ni];
    }

    // ---------------- phase 2: 4 chunks of 16 px (fully unrolled; acc1 indices compile-time)
#pragma unroll
    for (int pxq = 0; pxq < 4; ++pxq) {
        const int mi = pxq & 1;
        __syncthreads();                       // prior LDS users (phase1 / ch,cl readers) done
        if (wr == (pxq >> 1)) {                // owning px-half; both wc waves write their o-half
#pragma unroll
            for (int ni = 0; ni < 8; ++ni) {
                int o1 = wc * 128 + ni * 16 + l15;
                int base = (o1 >> 3) * 8 + (o1 & 7);
#pragma unroll
                for (int r = 0; r < 4; ++r) {
                    int px_l = l4 * 4 + r;     // 0..15 within chunk
                    float y = fmaxf(acc1[mi][ni][r] * scl1[ni] + shf1[ni], 0.f);
                    u16 h, lo; split2(y, h, lo);
                    int pos = px_l * 280 + base;
                    q1[pos] = h;
                    q1[4480 + pos] = lo;
                }
            }
        }
        __syncthreads();                       // q1 visible

        f32x4 acc2[4];
#pragma unroll
        for (int ni = 0; ni < 4; ++ni) acc2[ni] = f32x4{0.f, 0.f, 0.f, 0.f};

#pragma unroll
        for (int s2 = 0; s2 < 8; ++s2) {       // K2=256, barrier-free: q1 read-only, W2 from global
            int ap = l15 * 280 + (s2 * 4 + l4) * 8;
            bf16x8 a2h = *reinterpret_cast<const bf16x8*>(&q1[ap]);
            bf16x8 a2m = *reinterpret_cast<const bf16x8*>(&q1[4480 + ap]);
#pragma unroll
            for (int ni = 0; ni < 4; ++ni) {
                size_t boff = (size_t)(w * 64 + ni * 16 + l15) * 256 + s2 * 32 + l4 * 8;
                bf16x8 b2h = *reinterpret_cast<const bf16x8*>(&a.W2h[boff]);
                bf16x8 b2l = *reinterpret_cast<const bf16x8*>(&a.W2l[boff]);
                acc2[ni] = __builtin_amdgcn_mfma_f32_16x16x32_bf16(a2h, b2h, acc2[ni], 0, 0, 0);
                acc2[ni] = __builtin_amdgcn_mfma_f32_16x16x32_bf16(a2h, b2l, acc2[ni], 0, 0, 0);
                acc2[ni] = __builtin_amdgcn_mfma_f32_16x16x32_bf16(a2m, b2h, acc2[ni], 0, 0, 0);
            }
        }
        __syncthreads();                       // q1 reads done before tf overwrites (alias)

        // q2 = BN2+ReLU -> tf [16][260] fp32
#pragma unroll
        for (int ni = 0; ni < 4; ++ni) {
            int o2 = w * 64 + ni * 16 + l15;
#pragma unroll
            for (int r = 0; r < 4; ++r) {
                int px_l = l4 * 4 + r;
                tf[px_l * 260 + o2] = fmaxf(acc2[ni][r] * scl2[ni] + shf2[ni], 0.f);
            }
        }
        __syncthreads();

        // ---- attention for these 16 px ----
        {   // sim partials: px = t&15, cg = t>>4 handles 16 channels
            const int px = t & 15, cg = t >> 4;
            float sim[19];
#pragma unroll
            for (int kk = 0; kk < 19; ++kk) sim[kk] = 0.f;
#pragma unroll 4
            for (int i = 0; i < 16; ++i) {
                int c = cg * 16 + i;
                float qv = tf[px * 260 + c];
#pragma unroll
                for (int kk = 0; kk < 19; ++kk) sim[kk] += qv * kl[c * 19 + kk];
            }
#pragma unroll
            for (int kk = 0; kk < 19; ++kk) sp[(cg * 16 + px) * 20 + kk] = sim[kk];
        }
        __syncthreads();                       // tf reads + sp writes done
        {   // reduce + softmax (redundant per px) + ctx
            const int px = t & 15, cg = t >> 4;
            float wgt[19];
            float mx = -1e30f;
#pragma unroll
            for (int kk = 0; kk < 19; ++kk) {
                float s0 = 0.f;
#pragma unroll 4
                for (int g = 0; g < 16; ++g) s0 += sp[(g * 16 + px) * 20 + kk];
                wgt[kk] = s0 * 0.0625f;
                mx = fmaxf(mx, wgt[kk]);
            }
            float ssum = 0.f;
#pragma unroll
            for (int kk = 0; kk < 19; ++kk) { wgt[kk] = __expf(wgt[kk] - mx); ssum += wgt[kk]; }
            const float inv = 1.f / ssum;
#pragma unroll
            for (int kk = 0; kk < 19; ++kk) wgt[kk] *= inv;
#pragma unroll 4
            for (int i = 0; i < 16; ++i) {     // ctx hi/lo staging (regions disjoint from sp)
                int c = cg * 16 + i;
                float acc = 0.f;
#pragma unroll
                for (int kk = 0; kk < 19; ++kk) acc += wgt[kk] * vl[kk * 256 + c];
                u16 h, lo; split2(acc, h, lo);
                ch[px * 264 + c] = h;
                cl[px * 264 + c] = lo;
            }
        }
        __syncthreads();                       // staging complete
        // coalesced ctx stores: 16 rows x 256 u16 per plane
#pragma unroll
        for (int j = 0; j < 2; ++j) {
            int task = j * 256 + t;
            int row = task >> 5, seg = task & 31;
            size_t go = (size_t)(mg + pxq * 16 + row) * 256 + seg * 8;
            *reinterpret_cast<uint4*>(&a.ctxh[go]) =
                *reinterpret_cast<const uint4*>(&ch[row * 264 + seg * 8]);
            *reinterpret_cast<uint4*>(&a.ctxl[go]) =
                *reinterpret_cast<const uint4*>(&cl[row * 264 + seg * 8]);
        }
    }
}

// ---------------------------------------------------------------- gemm_up: ctx(split planes) -> out[b][o][n] fp32
// Barrier-free main loop (validated R13); now 4 waves/EU for 2x TLP (VGPR 92 <= 128 budget).
struct GUArgs {
    const u16 *Ah, *Al, *Wh, *Wl;
    const float *gg, *bbv, *mmv, *vvv;
    float* Yf;
};
__global__ __launch_bounds__(256, 4) void gemm_up_kernel(GUArgs a) {
    __shared__ float ldsf[128 * 68];          // epilogue only (34816 B)
    const int t = threadIdx.x;
    const int l = t & 63;
    const int w = t >> 6;
    const int wr = w >> 1, wc = w & 1;
    const int l15 = l & 15, l4 = l >> 4;
    const int id = blockIdx.y * 4 + blockIdx.x;
    const int wid = (id & 7) * 1024 + (id >> 3);  // bijective XCD chunking (nwg=8192)
    const int o0 = (wid & 3) * 128;
    const int m  = (wid >> 2) * 64;
    const int bb = m >> 14;
    const int nb = m & 16383;

    f32x4 acc[2][4];
#pragma unroll
    for (int mi = 0; mi < 2; ++mi)
#pragma unroll
        for (int ni = 0; ni < 4; ++ni) acc[mi][ni] = f32x4{0.f, 0.f, 0.f, 0.f};

    size_t abase[2], wbase[4];
#pragma unroll
    for (int mi = 0; mi < 2; ++mi)
        abase[mi] = (size_t)(m + wr * 32 + mi * 16 + l15) * 256 + l4 * 8;
#pragma unroll
    for (int ni = 0; ni < 4; ++ni)
        wbase[ni] = (size_t)(o0 + wc * 64 + ni * 16 + l15) * 256 + l4 * 8;

#pragma unroll 2
    for (int s = 0; s < 8; ++s) {             // K=256 in 8 steps of 32, barrier-free
        const int ko = s * 32;
        bf16x8 ah[2], al[2], bh[4], bl[4];
#pragma unroll
        for (int mi = 0; mi < 2; ++mi) {
            ah[mi] = *reinterpret_cast<const bf16x8*>(a.Ah + abase[mi] + ko);
            al[mi] = *reinterpret_cast<const bf16x8*>(a.Al + abase[mi] + ko);
        }
#pragma unroll
        for (int ni = 0; ni < 4; ++ni) {
            bh[ni] = *reinterpret_cast<const bf16x8*>(a.Wh + wbase[ni] + ko);
            bl[ni] = *reinterpret_cast<const bf16x8*>(a.Wl + wbase[ni] + ko);
        }
#pragma unroll
        for (int mi = 0; mi < 2; ++mi)
#pragma unroll
            for (int ni = 0; ni < 4; ++ni) {
                acc[mi][ni] = __builtin_amdgcn_mfma_f32_16x16x32_bf16(ah[mi], bh[ni], acc[mi][ni], 0, 0, 0);
                acc[mi][ni] = __builtin_amdgcn_mfma_f32_16x16x32_bf16(ah[mi], bl[ni], acc[mi][ni], 0, 0, 0);
                acc[mi][ni] = __builtin_amdgcn_mfma_f32_16x16x32_bf16(al[mi], bh[ni], acc[mi][ni], 0, 0, 0);
            }
    }

    float scl[4], shf[4];
#pragma unroll
    for (int ni = 0; ni < 4; ++ni) {
        int o = o0 + wc * 64 + ni * 16 + l15;
        scl[ni] = a.gg[o] * __frsqrt_rn(a.vvv[o] + 1e-5f);
        shf[ni] = a.bbv[o] - a.mmv[o] * scl[ni];
    }

    // epilogue: transpose via LDS [128 o][68 n] f32 -> out[b][o][16384] coalesced
#pragma unroll
    for (int ni = 0; ni < 4; ++ni) {
        int o_l = wc * 64 + ni * 16 + l15;
#pragma unroll
        for (int mi = 0; mi < 2; ++mi)
#pragma unroll
            for (int r = 0; r < 4; ++r) {
                int n_l = wr * 32 + mi * 16 + l4 * 4 + r;
                float y = fmaxf(acc[mi][ni][r] * scl[ni] + shf[ni], 0.f);
                ldsf[o_l * 68 + n_l] = y;
            }
    }
    __syncthreads();
#pragma unroll
    for (int j = 0; j < 8; ++j) {
        int idx = j * 256 + t;
        int row = idx >> 4, c4 = (idx & 15) * 4;
        *reinterpret_cast<float4*>(&a.Yf[((size_t)bb << 23) + (size_t)(o0 + row) * 16384 + nb + c4]) =
            *reinterpret_cast<const float4*>(&ldsf[row * 68 + c4]);
    }
}

// ---------------------------------------------------------------- launch
extern "C" void kernel_launch(void* const* d_in, const int* in_sizes, int n_in,
                              void* d_out, int out_size, void* d_ws, size_t ws_size,
                              hipStream_t stream) {
    const float* x     = (const float*)d_in[0];
    const float* proxy = (const float*)d_in[1];
    const float* pw1 = (const float*)d_in[2];
    const float* pg1 = (const float*)d_in[3];
    const float* pb1 = (const float*)d_in[4];
    const float* pm1 = (const float*)d_in[5];
    const float* pv1 = (const float*)d_in[6];
    const float* pw2 = (const float*)d_in[7];
    const float* pg2 = (const float*)d_in[8];
    const float* pb2 = (const float*)d_in[9];
    const float* pm2 = (const float*)d_in[10];
    const float* pv2 = (const float*)d_in[11];
    const float* ow1 = (const float*)d_in[12];
    const float* og1 = (const float*)d_in[13];
    const float* ob1 = (const float*)d_in[14];
    const float* om1 = (const float*)d_in[15];
    const float* ov1 = (const float*)d_in[16];
    const float* ow2 = (const float*)d_in[17];
    const float* og2 = (const float*)d_in[18];
    const float* ob2 = (const float*)d_in[19];
    const float* om2 = (const float*)d_in[20];
    const float* ov2 = (const float*)d_in[21];
    const float* dw  = (const float*)d_in[22];
    const float* dg  = (const float*)d_in[23];
    const float* db  = (const float*)d_in[24];
    const float* dm  = (const float*)d_in[25];
    const float* dv  = (const float*)d_in[26];
    const float* uw  = (const float*)d_in[27];
    const float* ug  = (const float*)d_in[28];
    const float* ub  = (const float*)d_in[29];
    const float* um  = (const float*)d_in[30];
    const float* uv  = (const float*)d_in[31];

    char* ws = (char*)d_ws;
    u16* wpw1h = (u16*)(ws + 0);                 // 262144 B
    u16* wpw1l = (u16*)(ws + 262144);
    u16* wpw2h = (u16*)(ws + 524288);            // 131072 B
    u16* wpw2l = (u16*)(ws + 655360);
    u16* wuwh  = (u16*)(ws + 786432);            // 262144 B
    u16* wuwl  = (u16*)(ws + 1048576);
    float* kmat = (float*)(ws + 1310720);        // 155648 B
    float* vmat = (float*)(ws + 1466368);        // 155648 B -> ends 1622016
    u16* ctxh = (u16*)(ws + 2097152);            // 67108864 B
    u16* ctxl = (u16*)(ws + 69206016);           // 67108864 B -> ends 136314880

    convert_split_kernel<<<512, 256, 0, stream>>>(pw1, wpw1h, wpw1l, 131072);
    convert_split_kernel<<<256, 256, 0, stream>>>(pw2, wpw2h, wpw2l, 65536);
    convert_split_kernel<<<512, 256, 0, stream>>>(uw,  wuwh,  wuwl,  131072);

    KVArgs ka{proxy, ow1, og1, ob1, om1, ov1, ow2, og2, ob2, om2, ov2,
              dw, dg, db, dm, dv, kmat, vmat};
    kv_kernel<<<8, 256, 0, stream>>>(ka);

    // fused: x -> q1 -> q2 -> attention -> ctx (no q2f round-trip, no attn kernel)
    F12Args fa{x, wpw1h, wpw1l, wpw2h, wpw2l,
               pg1, pb1, pm1, pv1, pg2, pb2, pm2, pv2, kmat, vmat, ctxh, ctxl};
    fused12_kernel<<<2048, 256, 0, stream>>>(fa);

    // gemm_up: ctx -> out[b][o][n] fp32, K=256, COUT=512, 64x128 tiles
    GUArgs ga{ctxh, ctxl, wuwh, wuwl, ug, ub, um, uv, (float*)d_out};
    gemm_up_kernel<<<dim3(4, 2048), 256, 0, stream>>>(ga);
}

// Round 16
// 991.087 us; speedup vs baseline: 1.0218x; 1.0118x over previous
//
#include <hip/hip_runtime.h>

typedef unsigned int u32;
typedef unsigned short u16;
typedef __attribute__((ext_vector_type(8))) short bf16x8;
typedef __attribute__((ext_vector_type(4))) float f32x4;

#define DEVI static __device__ __forceinline__

DEVI u16 f2bf(float f) {
    u32 u = __float_as_uint(f);
    u32 r = u + 0x7FFFu + ((u >> 16) & 1u);   // RNE (inputs finite)
    return (u16)(r >> 16);
}
DEVI float bf2f(u16 s) { return __uint_as_float(((u32)s) << 16); }
DEVI void split2(float a, u16& h, u16& l) {   // a ≈ hi + lo, residual ≤ 2^-18|a|
    h = f2bf(a);
    l = f2bf(a - bf2f(h));
}
DEVI int swz(int row) { return (row & 3) ^ ((row >> 2) & 3); }  // 32-col-tile swizzle key

// direct global->LDS DMA, 16 B/lane; LDS dest = wave-uniform base + lane*16
DEVI void gload16(const void* g, void* l) {
    __builtin_amdgcn_global_load_lds(
        (const __attribute__((address_space(1))) u32*)g,
        (__attribute__((address_space(3))) u32*)l, 16, 0, 0);
}

union U4 { uint4 v; u16 s[8]; };

// ---------------------------------------------------------------- f32 -> (hi,lo) bf16 planes
__global__ __launch_bounds__(256) void convert_split_kernel(const float* __restrict__ in,
                                                            u16* __restrict__ hi,
                                                            u16* __restrict__ lo, int n) {
    int i = blockIdx.x * 256 + threadIdx.x;
    if (i < n) { u16 h, l; split2(in[i], h, l); hi[i] = h; lo[i] = l; }
}

// ---------------------------------------------------------------- proxy-side K/V (tiny, fp32 VALU)
struct KVArgs {
    const float *proxy;
    const float *ow1, *og1, *ob1, *om1, *ov1;
    const float *ow2, *og2, *ob2, *om2, *ov2;
    const float *dw,  *dg,  *db,  *dm,  *dv;
    float *kmat;   // [B][256][19]
    float *vmat;   // [B][19][256]
};
__global__ __launch_bounds__(256) void kv_kernel(KVArgs a) {
    __shared__ float pl[512 * 19];
    __shared__ float t1[256 * 19];
    const int t = threadIdx.x;
    const int b = blockIdx.x;
    const float* pb = a.proxy + (size_t)b * 512 * 19;
    for (int i = t; i < 512 * 19; i += 256) pl[i] = pb[i];
    __syncthreads();
    const int o = t;
    {
        float acc[19] = {0.f};
        const float* wr = a.ow1 + (size_t)o * 512;
        for (int c = 0; c < 512; ++c) {
            float wv = wr[c];
#pragma unroll
            for (int kk = 0; kk < 19; ++kk) acc[kk] += wv * pl[c * 19 + kk];
        }
        float sc = a.og1[o] * __frsqrt_rn(a.ov1[o] + 1e-5f);
        float sh = a.ob1[o] - a.om1[o] * sc;
#pragma unroll
        for (int kk = 0; kk < 19; ++kk) t1[o * 19 + kk] = fmaxf(acc[kk] * sc + sh, 0.f);
    }
    __syncthreads();
    {
        float acc[19] = {0.f};
        const float* wr = a.ow2 + (size_t)o * 256;
        for (int c = 0; c < 256; ++c) {
            float wv = wr[c];
#pragma unroll
            for (int kk = 0; kk < 19; ++kk) acc[kk] += wv * t1[c * 19 + kk];
        }
        float sc = a.og2[o] * __frsqrt_rn(a.ov2[o] + 1e-5f);
        float sh = a.ob2[o] - a.om2[o] * sc;
#pragma unroll
        for (int kk = 0; kk < 19; ++kk)
            a.kmat[((size_t)b * 256 + o) * 19 + kk] = fmaxf(acc[kk] * sc + sh, 0.f);
    }
    {
        float acc[19] = {0.f};
        const float* wr = a.dw + (size_t)o * 512;
        for (int c = 0; c < 512; ++c) {
            float wv = wr[c];
#pragma unroll
            for (int kk = 0; kk < 19; ++kk) acc[kk] += wv * pl[c * 19 + kk];
        }
        float sc = a.dg[o] * __frsqrt_rn(a.dv[o] + 1e-5f);
        float sh = a.db[o] - a.dm[o] * sc;
#pragma unroll
        for (int kk = 0; kk < 19; ++kk)
            a.vmat[((size_t)b * 19 + kk) * 256 + o] = fmaxf(acc[kk] * sc + sh, 0.f);
    }
}

// ---------------------------------------------------------------- attention: 2 threads/px, 128 px/block
// grid = mpix/128 -> 1024 blocks, 3 blocks/CU (49.6 KB LDS). Partial sims exchanged via
// sp[128][21] (stride 21, gcd(21,32)=1 -> conflict-free). Same math as R13 attn.
struct AttnArgs { const float* q2f; const float* kmat; const float* vmat;
                  u16* ctxh; u16* ctxl; long long p_off; };
__global__ __launch_bounds__(256, 3) void attn_kernel(AttnArgs a) {
    __shared__ float kl[4864];        // [c][19]
    __shared__ float vl[4864];        // [kk][256]
    __shared__ float sp[128 * 21];    // partial sims / shared weights
    const int t = threadIdx.x;
    const int px = t & 127, hf = t >> 7;               // wave-uniform hf (waves 0,1 -> 0; 2,3 -> 1)
    const size_t pl_ = (size_t)blockIdx.x * 128;       // pass-local pixel base
    const size_t pg  = (size_t)a.p_off + pl_;          // global pixel base
    const int b = (int)(pg >> 14);                     // 128 | 16384 -> no batch straddle
    for (int i = t; i < 4864; i += 256) { kl[i] = a.kmat[(size_t)b * 4864 + i];
                                          vl[i] = a.vmat[(size_t)b * 4864 + i]; }
    __syncthreads();
    // sim over this thread's 128-channel half (q reads: per-lane 512B rows, fp32 float4)
    const float* qrow = a.q2f + (pl_ + px) * 256 + hf * 128;
    float sim[19];
#pragma unroll
    for (int kk = 0; kk < 19; ++kk) sim[kk] = 0.f;
    for (int j = 0; j < 32; ++j) {
        float4 qv = reinterpret_cast<const float4*>(qrow)[j];
#pragma unroll
        for (int e = 0; e < 4; ++e) {
            float qf = (e == 0) ? qv.x : (e == 1) ? qv.y : (e == 2) ? qv.z : qv.w;
            int c = hf * 128 + j * 4 + e;
#pragma unroll
            for (int kk = 0; kk < 19; ++kk) sim[kk] += qf * kl[c * 19 + kk];  // broadcast
        }
    }
    if (hf == 1) {
#pragma unroll
        for (int kk = 0; kk < 19; ++kk) sp[px * 21 + kk] = sim[kk];
    }
    __syncthreads();
    if (hf == 0) {                     // combine halves + softmax, publish weights
        float mx = -1e30f;
#pragma unroll
        for (int kk = 0; kk < 19; ++kk) {
            sim[kk] = (sim[kk] + sp[px * 21 + kk]) * 0.0625f;
            mx = fmaxf(mx, sim[kk]);
        }
        float ssum = 0.f;
#pragma unroll
        for (int kk = 0; kk < 19; ++kk) { sim[kk] = __expf(sim[kk] - mx); ssum += sim[kk]; }
        const float inv = 1.f / ssum;
#pragma unroll
        for (int kk = 0; kk < 19; ++kk) sp[px * 21 + kk] = sim[kk] * inv;
    }
    __syncthreads();
    float wgt[19];
#pragma unroll
    for (int kk = 0; kk < 19; ++kk) wgt[kk] = sp[px * 21 + kk];
    // ctx for this half's 128 channels
    u16* crh = a.ctxh + (pg + px) * 256 + hf * 128;
    u16* crl = a.ctxl + (pg + px) * 256 + hf * 128;
    for (int j = 0; j < 16; ++j) {
        U4 hh, ll;
#pragma unroll
        for (int e = 0; e < 8; ++e) {
            int c = hf * 128 + j * 8 + e;
            float acc = 0.f;
#pragma unroll
            for (int kk = 0; kk < 19; ++kk) acc += wgt[kk] * vl[kk * 256 + c];  // broadcast
            split2(acc, hh.s[e], ll.s[e]);
        }
        *reinterpret_cast<uint4*>(crh + j * 8) = hh.v;
        *reinterpret_cast<uint4*>(crl + j * 8) = ll.v;
    }
}

// ---------------------------------------------------------------- FUSED gemm1+gemm2, 64-px blocks, 2 blocks/CU
// (benched R13 structure, 394 us): xs dbuf 16 KB + wb dbuf 64 KB, 1 barrier/step;
// phase 2: W2 direct-from-global, q1 LDS 280-u16 rows, barrier-free s2 loop.
struct F12Args {
    const float* Xf;
    const u16 *W1h, *W1l, *W2h, *W2l;
    const float *g1, *b1, *m1, *v1;
    const float *g2, *b2, *m2, *v2;
    float* q2f;     // pass-local [chunk_px][256] fp32
    int m_off;
};
__global__ __launch_bounds__(256, 2) void fused12_kernel(F12Args a) {
    __shared__ char LB[81920];
    u16* xs = (u16*)LB;               // 2 buf x 2 planes x [64][32] u16  (16384 B)
    u16* wb = (u16*)(LB + 16384);     // 2 buf x 2 planes x [256][32] u16 (65536 B)
    u16* q1 = (u16*)LB;               // phase2: 2 planes x 16 rows x 280 u16 (17920 B)
    float* tf = (float*)LB;           // epilogue: [16][260] f32 (16640 B), aliases q1

    const int t = threadIdx.x;
    const int l = t & 63, w = t >> 6;
    const int wr = w >> 1, wc = w & 1;
    const int l15 = l & 15, l4 = l >> 4;
    const int mloc = blockIdx.x * 64;
    const int mg = a.m_off + mloc;
    const int bb = mg >> 14, nb = mg & 16383;   // 64 | 16384 -> no batch straddle

    f32x4 acc1[2][8];
#pragma unroll
    for (int mi = 0; mi < 2; ++mi)
#pragma unroll
        for (int ni = 0; ni < 8; ++ni) acc1[mi][ni] = f32x4{0.f, 0.f, 0.f, 0.f};

    float fx[8];

    // per-lane DMA source precompute (lane-only swizzle: 16-row groups)
    const int dsw = ((l & 3) ^ ((l >> 2) & 3) ^ ((l >> 4) & 3)) * 8;  // source col offset (u16)
    const int drow = l >> 2;                                           // row within 16-row group

    auto loadX = [&](int s) {
        const int px = t & 63, oct = t >> 6;     // 256 tasks: 64 px x 4 octs
        const float* src = a.Xf + (((size_t)bb * 512 + s * 32 + oct * 8) << 14) + nb + px;
#pragma unroll
        for (int e = 0; e < 8; ++e) fx[e] = src[(size_t)e << 14];
    };
    auto writeX = [&](int buf) {
        const int px = t & 63, oct = t >> 6;
        U4 ph, plo;
#pragma unroll
        for (int e = 0; e < 8; ++e) split2(fx[e], ph.s[e], plo.s[e]);
        int pos = buf * 4096 + px * 32 + ((oct ^ swz(px)) * 8);
        *reinterpret_cast<uint4*>(&xs[pos]) = ph.v;
        *reinterpret_cast<uint4*>(&xs[2048 + pos]) = plo.v;
    };
    auto dmaW1 = [&](int s, int buf) {
#pragma unroll
        for (int i = 0; i < 8; ++i) {
            const int p = i >> 2, g = i & 3;
            const int row16 = w * 64 + g * 16;
            const u16* src = (p ? a.W1l : a.W1h) + (size_t)(row16 + drow) * 512 + s * 32 + dsw;
            u16* dst = &wb[buf * 16384 + p * 8192 + row16 * 32];
            gload16(src, dst);
        }
    };

    // ---------------- phase 1: K=512 in 16 steps of 32, single barrier/step
    loadX(0); dmaW1(0, 0);
    writeX(0);
    loadX(1);
    __syncthreads();
    int cur = 0;
    for (int s = 0; s < 16; ++s) {
        if (s < 15) dmaW1(s + 1, cur ^ 1);
        bf16x8 ah[2], am[2];
#pragma unroll
        for (int mi = 0; mi < 2; ++mi) {
            int ar = wr * 32 + mi * 16 + l15;
            int ap = cur * 4096 + ar * 32 + ((l4 ^ swz(ar)) * 8);
            ah[mi] = *reinterpret_cast<const bf16x8*>(&xs[ap]);
            am[mi] = *reinterpret_cast<const bf16x8*>(&xs[2048 + ap]);
        }
#pragma unroll
        for (int ni = 0; ni < 8; ++ni) {
            int br = wc * 128 + ni * 16 + l15;
            int bp = cur * 16384 + br * 32 + ((l4 ^ swz(br)) * 8);
            bf16x8 bh = *reinterpret_cast<const bf16x8*>(&wb[bp]);
            bf16x8 bl_ = *reinterpret_cast<const bf16x8*>(&wb[8192 + bp]);
#pragma unroll
            for (int mi = 0; mi < 2; ++mi) {
                acc1[mi][ni] = __builtin_amdgcn_mfma_f32_16x16x32_bf16(ah[mi], bh, acc1[mi][ni], 0, 0, 0);
                acc1[mi][ni] = __builtin_amdgcn_mfma_f32_16x16x32_bf16(ah[mi], bl_, acc1[mi][ni], 0, 0, 0);
                acc1[mi][ni] = __builtin_amdgcn_mfma_f32_16x16x32_bf16(am[mi], bh, acc1[mi][ni], 0, 0, 0);
            }
        }
        if (s < 15) {
            writeX(cur ^ 1);
            if (s < 14) loadX(s + 2);
        }
        __syncthreads();
        cur ^= 1;
    }

    // BN coefficients
    float scl1[8], shf1[8];
#pragma unroll
    for (int ni = 0; ni < 8; ++ni) {
        int o = wc * 128 + ni * 16 + l15;
        scl1[ni] = a.g1[o] * __frsqrt_rn(a.v1[o] + 1e-5f);
        shf1[ni] = a.b1[o] - a.m1[o] * scl1[ni];
    }
    float scl2[4], shf2[4];
#pragma unroll
    for (int ni = 0; ni < 4; ++ni) {
        int o = w * 64 + ni * 16 + l15;
        scl2[ni] = a.g2[o] * __frsqrt_rn(a.v2[o] + 1e-5f);
        shf2[ni] = a.b2[o] - a.m2[o] * scl2[ni];
    }

    // ---------------- phase 2: 4 chunks of 16 px (fully unrolled; acc1 indices compile-time)
#pragma unroll
    for (int pxq = 0; pxq < 4; ++pxq) {
        const int mi = pxq & 1;
        __syncthreads();                       // prior LDS users (phase1 / tf readers) done
        if (wr == (pxq >> 1)) {                // owning px-half; both wc waves write their o-half
#pragma unroll
            for (int ni = 0; ni < 8; ++ni) {
                int o1 = wc * 128 + ni * 16 + l15;
                int base = (o1 >> 3) * 8 + (o1 & 7);
#pragma unroll
                for (int r = 0; r < 4; ++r) {
                    int px_l = l4 * 4 + r;     // 0..15 within chunk
                    float y = fmaxf(acc1[mi][ni][r] * scl1[ni] + shf1[ni], 0.f);
                    u16 h, lo; split2(y, h, lo);
                    int pos = px_l * 280 + base;
                    q1[pos] = h;
                    q1[4480 + pos] = lo;       // lo plane at +8960 B
                }
            }
        }
        __syncthreads();                       // q1 visible to all waves

        f32x4 acc2[4];
#pragma unroll
        for (int ni = 0; ni < 4; ++ni) acc2[ni] = f32x4{0.f, 0.f, 0.f, 0.f};

#pragma unroll
        for (int s2 = 0; s2 < 8; ++s2) {       // K2=256, barrier-free: q1 read-only, W2 from global
            int ap = l15 * 280 + (s2 * 4 + l4) * 8;
            bf16x8 a2h = *reinterpret_cast<const bf16x8*>(&q1[ap]);
            bf16x8 a2m = *reinterpret_cast<const bf16x8*>(&q1[4480 + ap]);
#pragma unroll
            for (int ni = 0; ni < 4; ++ni) {
                size_t boff = (size_t)(w * 64 + ni * 16 + l15) * 256 + s2 * 32 + l4 * 8;
                bf16x8 b2h = *reinterpret_cast<const bf16x8*>(&a.W2h[boff]);
                bf16x8 b2l = *reinterpret_cast<const bf16x8*>(&a.W2l[boff]);
                acc2[ni] = __builtin_amdgcn_mfma_f32_16x16x32_bf16(a2h, b2h, acc2[ni], 0, 0, 0);
                acc2[ni] = __builtin_amdgcn_mfma_f32_16x16x32_bf16(a2h, b2l, acc2[ni], 0, 0, 0);
                acc2[ni] = __builtin_amdgcn_mfma_f32_16x16x32_bf16(a2m, b2h, acc2[ni], 0, 0, 0);
            }
        }
        __syncthreads();                       // all q1 reads done before tf overwrites (alias)

        // epilogue: BN2+ReLU -> tf [16][260] f32 -> coalesced float4 stores
#pragma unroll
        for (int ni = 0; ni < 4; ++ni) {
            int o2 = w * 64 + ni * 16 + l15;
#pragma unroll
            for (int r = 0; r < 4; ++r) {
                int px_l = l4 * 4 + r;
                tf[px_l * 260 + o2] = fmaxf(acc2[ni][r] * scl2[ni] + shf2[ni], 0.f);
            }
        }
        __syncthreads();
#pragma unroll
        for (int j = 0; j < 4; ++j) {          // 16 rows x 256 f32
            int task = j * 256 + t;
            int row = task >> 6, c4 = task & 63;
            *reinterpret_cast<float4*>(&a.q2f[(size_t)(mloc + pxq * 16 + row) * 256 + c4 * 4]) =
                *reinterpret_cast<const float4*>(&tf[row * 260 + c4 * 4]);
        }
    }
}

// ---------------------------------------------------------------- gemm_up: ctx(split planes) -> out[b][o][n] fp32
// Barrier-free main loop (benched R13); 4 waves/EU for 2x TLP (VGPR 92 <= 128 budget, ran in R15).
struct GUArgs {
    const u16 *Ah, *Al, *Wh, *Wl;
    const float *gg, *bbv, *mmv, *vvv;
    float* Yf;
};
__global__ __launch_bounds__(256, 4) void gemm_up_kernel(GUArgs a) {
    __shared__ float ldsf[128 * 68];          // epilogue only (34816 B)
    const int t = threadIdx.x;
    const int l = t & 63;
    const int w = t >> 6;
    const int wr = w >> 1, wc = w & 1;
    const int l15 = l & 15, l4 = l >> 4;
    const int id = blockIdx.y * 4 + blockIdx.x;
    const int wid = (id & 7) * 1024 + (id >> 3);  // bijective XCD chunking (nwg=8192)
    const int o0 = (wid & 3) * 128;
    const int m  = (wid >> 2) * 64;
    const int bb = m >> 14;
    const int nb = m & 16383;

    f32x4 acc[2][4];
#pragma unroll
    for (int mi = 0; mi < 2; ++mi)
#pragma unroll
        for (int ni = 0; ni < 4; ++ni) acc[mi][ni] = f32x4{0.f, 0.f, 0.f, 0.f};

    size_t abase[2], wbase[4];
#pragma unroll
    for (int mi = 0; mi < 2; ++mi)
        abase[mi] = (size_t)(m + wr * 32 + mi * 16 + l15) * 256 + l4 * 8;
#pragma unroll
    for (int ni = 0; ni < 4; ++ni)
        wbase[ni] = (size_t)(o0 + wc * 64 + ni * 16 + l15) * 256 + l4 * 8;

#pragma unroll 2
    for (int s = 0; s < 8; ++s) {             // K=256 in 8 steps of 32, barrier-free
        const int ko = s * 32;
        bf16x8 ah[2], al[2], bh[4], bl[4];
#pragma unroll
        for (int mi = 0; mi < 2; ++mi) {
            ah[mi] = *reinterpret_cast<const bf16x8*>(a.Ah + abase[mi] + ko);
            al[mi] = *reinterpret_cast<const bf16x8*>(a.Al + abase[mi] + ko);
        }
#pragma unroll
        for (int ni = 0; ni < 4; ++ni) {
            bh[ni] = *reinterpret_cast<const bf16x8*>(a.Wh + wbase[ni] + ko);
            bl[ni] = *reinterpret_cast<const bf16x8*>(a.Wl + wbase[ni] + ko);
        }
#pragma unroll
        for (int mi = 0; mi < 2; ++mi)
#pragma unroll
            for (int ni = 0; ni < 4; ++ni) {
                acc[mi][ni] = __builtin_amdgcn_mfma_f32_16x16x32_bf16(ah[mi], bh[ni], acc[mi][ni], 0, 0, 0);
                acc[mi][ni] = __builtin_amdgcn_mfma_f32_16x16x32_bf16(ah[mi], bl[ni], acc[mi][ni], 0, 0, 0);
                acc[mi][ni] = __builtin_amdgcn_mfma_f32_16x16x32_bf16(al[mi], bh[ni], acc[mi][ni], 0, 0, 0);
            }
    }

    float scl[4], shf[4];
#pragma unroll
    for (int ni = 0; ni < 4; ++ni) {
        int o = o0 + wc * 64 + ni * 16 + l15;
        scl[ni] = a.gg[o] * __frsqrt_rn(a.vvv[o] + 1e-5f);
        shf[ni] = a.bbv[o] - a.mmv[o] * scl[ni];
    }

    // epilogue: transpose via LDS [128 o][68 n] f32 -> out[b][o][16384] coalesced
#pragma unroll
    for (int ni = 0; ni < 4; ++ni) {
        int o_l = wc * 64 + ni * 16 + l15;
#pragma unroll
        for (int mi = 0; mi < 2; ++mi)
#pragma unroll
            for (int r = 0; r < 4; ++r) {
                int n_l = wr * 32 + mi * 16 + l4 * 4 + r;
                float y = fmaxf(acc[mi][ni][r] * scl[ni] + shf[ni], 0.f);
                ldsf[o_l * 68 + n_l] = y;
            }
    }
    __syncthreads();
#pragma unroll
    for (int j = 0; j < 8; ++j) {
        int idx = j * 256 + t;
        int row = idx >> 4, c4 = (idx & 15) * 4;
        *reinterpret_cast<float4*>(&a.Yf[((size_t)bb << 23) + (size_t)(o0 + row) * 16384 + nb + c4]) =
            *reinterpret_cast<const float4*>(&ldsf[row * 68 + c4]);
    }
}

// ---------------------------------------------------------------- launch
extern "C" void kernel_launch(void* const* d_in, const int* in_sizes, int n_in,
                              void* d_out, int out_size, void* d_ws, size_t ws_size,
                              hipStream_t stream) {
    const float* x     = (const float*)d_in[0];
    const float* proxy = (const float*)d_in[1];
    const float* pw1 = (const float*)d_in[2];
    const float* pg1 = (const float*)d_in[3];
    const float* pb1 = (const float*)d_in[4];
    const float* pm1 = (const float*)d_in[5];
    const float* pv1 = (const float*)d_in[6];
    const float* pw2 = (const float*)d_in[7];
    const float* pg2 = (const float*)d_in[8];
    const float* pb2 = (const float*)d_in[9];
    const float* pm2 = (const float*)d_in[10];
    const float* pv2 = (const float*)d_in[11];
    const float* ow1 = (const float*)d_in[12];
    const float* og1 = (const float*)d_in[13];
    const float* ob1 = (const float*)d_in[14];
    const float* om1 = (const float*)d_in[15];
    const float* ov1 = (const float*)d_in[16];
    const float* ow2 = (const float*)d_in[17];
    const float* og2 = (const float*)d_in[18];
    const float* ob2 = (const float*)d_in[19];
    const float* om2 = (const float*)d_in[20];
    const float* ov2 = (const float*)d_in[21];
    const float* dw  = (const float*)d_in[22];
    const float* dg  = (const float*)d_in[23];
    const float* db  = (const float*)d_in[24];
    const float* dm  = (const float*)d_in[25];
    const float* dv  = (const float*)d_in[26];
    const float* uw  = (const float*)d_in[27];
    const float* ug  = (const float*)d_in[28];
    const float* ub  = (const float*)d_in[29];
    const float* um  = (const float*)d_in[30];
    const float* uv  = (const float*)d_in[31];

    char* ws = (char*)d_ws;
    u16* wpw1h = (u16*)(ws + 0);                 // 262144 B
    u16* wpw1l = (u16*)(ws + 262144);
    u16* wpw2h = (u16*)(ws + 524288);            // 131072 B
    u16* wpw2l = (u16*)(ws + 655360);
    u16* wuwh  = (u16*)(ws + 786432);            // 262144 B
    u16* wuwl  = (u16*)(ws + 1048576);
    float* kmat = (float*)(ws + 1310720);        // 155648 B
    float* vmat = (float*)(ws + 1466368);        // 155648 B -> ends 1622016
    u16* ctxh = (u16*)(ws + 2097152);            // 67108864 B
    u16* ctxl = (u16*)(ws + 69206016);           // 67108864 B -> ends 136314880
    float* q2f = (float*)(ws + 136314880ull);    // 134217728/passes B, [chunk][256] fp32

    int passes = 1;
    while (passes < 16 && 136314880ull + 134217728ull / (size_t)passes > ws_size) passes <<= 1;

    convert_split_kernel<<<512, 256, 0, stream>>>(pw1, wpw1h, wpw1l, 131072);
    convert_split_kernel<<<256, 256, 0, stream>>>(pw2, wpw2h, wpw2l, 65536);
    convert_split_kernel<<<512, 256, 0, stream>>>(uw,  wuwh,  wuwl,  131072);

    KVArgs ka{proxy, ow1, og1, ob1, om1, ov1, ow2, og2, ob2, om2, ov2,
              dw, dg, db, dm, dv, kmat, vmat};
    kv_kernel<<<8, 256, 0, stream>>>(ka);

    const int mpix = 131072 / passes;            // pixels per pass
    for (int p = 0; p < passes; ++p) {
        const int m_off = p * mpix;
        F12Args fa{x, wpw1h, wpw1l, wpw2h, wpw2l,
                   pg1, pb1, pm1, pv1, pg2, pb2, pm2, pv2, q2f, m_off};
        fused12_kernel<<<mpix / 64, 256, 0, stream>>>(fa);
        AttnArgs aa{q2f, kmat, vmat, ctxh, ctxl, (long long)m_off};
        attn_kernel<<<mpix / 128, 256, 0, stream>>>(aa);
    }

    // gemm_up: ctx -> out[b][o][n] fp32, K=256, COUT=512, 64x128 tiles
    GUArgs ga{ctxh, ctxl, wuwh, wuwl, ug, ub, um, uv, (float*)d_out};
    gemm_up_kernel<<<dim3(4, 2048), 256, 0, stream>>>(ga);
}

// Round 17
// 608.083 us; speedup vs baseline: 1.6655x; 1.6299x over previous
//
#include <hip/hip_runtime.h>

typedef unsigned int u32;
typedef unsigned short u16;
typedef __attribute__((ext_vector_type(8))) short bf16x8;
typedef __attribute__((ext_vector_type(4))) float f32x4;

#define DEVI static __device__ __forceinline__

DEVI u16 f2bf(float f) {
    u32 u = __float_as_uint(f);
    u32 r = u + 0x7FFFu + ((u >> 16) & 1u);   // RNE (inputs finite)
    return (u16)(r >> 16);
}
DEVI float bf2f(u16 s) { return __uint_as_float(((u32)s) << 16); }
DEVI void split2(float a, u16& h, u16& l) {   // a ≈ hi + lo, residual ≤ 2^-18|a|
    h = f2bf(a);
    l = f2bf(a - bf2f(h));
}
DEVI int swz(int row) { return (row & 3) ^ ((row >> 2) & 3); }  // 32-col-tile swizzle key

// direct global->LDS DMA, 16 B/lane; LDS dest = wave-uniform base + lane*16
DEVI void gload16(const void* g, void* l) {
    __builtin_amdgcn_global_load_lds(
        (const __attribute__((address_space(1))) u32*)g,
        (__attribute__((address_space(3))) u32*)l, 16, 0, 0);
}

union U4 { uint4 v; u16 s[8]; };

// ---------------------------------------------------------------- weight packing (split + permute to lane-linear order)
// W1 [256][512] -> per (s in 16): [rg 16][lane 64][8] ; value = W1[rg*16 + (l>>2)][s*32 + dsw(l)]
__global__ __launch_bounds__(256) void pack_w1_kernel(const float* __restrict__ wsrc,
                                                      u16* __restrict__ ph, u16* __restrict__ pl) {
    int i = blockIdx.x * 256 + threadIdx.x;          // 16384 octets
    int s = i >> 10, rem = i & 1023;
    int rg = rem >> 6, l = rem & 63;
    int row = rg * 16 + (l >> 2);
    int col = s * 32 + (((l & 3) ^ ((l >> 2) & 3) ^ ((l >> 4) & 3)) * 8);
    U4 hh, ll;
#pragma unroll
    for (int e = 0; e < 8; ++e) split2(wsrc[(size_t)row * 512 + col + e], hh.s[e], ll.s[e]);
    *reinterpret_cast<uint4*>(&ph[(size_t)i * 8]) = hh.v;
    *reinterpret_cast<uint4*>(&pl[(size_t)i * 8]) = ll.v;
}
// W2 [256][256] -> [(w*8+s2)][ni][lane][8] ; value = W2[w*64+ni*16+(l&15)][s2*32+(l>>4)*8]
__global__ __launch_bounds__(256) void pack_w2_kernel(const float* __restrict__ wsrc,
                                                      u16* __restrict__ ph, u16* __restrict__ pl) {
    int i = blockIdx.x * 256 + threadIdx.x;          // 8192 octets
    int w_ = i >> 11, s2 = (i >> 8) & 7, ni = (i >> 6) & 3, l = i & 63;
    int row = w_ * 64 + ni * 16 + (l & 15);
    int col = s2 * 32 + (l >> 4) * 8;
    U4 hh, ll;
#pragma unroll
    for (int e = 0; e < 8; ++e) split2(wsrc[(size_t)row * 256 + col + e], hh.s[e], ll.s[e]);
    *reinterpret_cast<uint4*>(&ph[(size_t)i * 8]) = hh.v;
    *reinterpret_cast<uint4*>(&pl[(size_t)i * 8]) = ll.v;
}
// uw [512][256] -> [o4][wc][s][ni][lane][8] ; value = uw[o4*128+wc*64+ni*16+(l&15)][s*32+(l>>4)*8]
__global__ __launch_bounds__(256) void pack_wu_kernel(const float* __restrict__ wsrc,
                                                      u16* __restrict__ ph, u16* __restrict__ pl) {
    int i = blockIdx.x * 256 + threadIdx.x;          // 16384 octets
    int o4 = i >> 12, wc = (i >> 11) & 1, s = (i >> 8) & 7, ni = (i >> 6) & 3, l = i & 63;
    int row = o4 * 128 + wc * 64 + ni * 16 + (l & 15);
    int col = s * 32 + (l >> 4) * 8;
    U4 hh, ll;
#pragma unroll
    for (int e = 0; e < 8; ++e) split2(wsrc[(size_t)row * 256 + col + e], hh.s[e], ll.s[e]);
    *reinterpret_cast<uint4*>(&ph[(size_t)i * 8]) = hh.v;
    *reinterpret_cast<uint4*>(&pl[(size_t)i * 8]) = ll.v;
}

// ---------------------------------------------------------------- proxy-side K/V (tiny, fp32 VALU)
struct KVArgs {
    const float *proxy;
    const float *ow1, *og1, *ob1, *om1, *ov1;
    const float *ow2, *og2, *ob2, *om2, *ov2;
    const float *dw,  *dg,  *db,  *dm,  *dv;
    float *kmat;   // [B][256][19]
    float *vmat;   // [B][19][256]
};
__global__ __launch_bounds__(256) void kv_kernel(KVArgs a) {
    __shared__ float pl[512 * 19];
    __shared__ float t1[256 * 19];
    const int t = threadIdx.x;
    const int b = blockIdx.x;
    const float* pb = a.proxy + (size_t)b * 512 * 19;
    for (int i = t; i < 512 * 19; i += 256) pl[i] = pb[i];
    __syncthreads();
    const int o = t;
    {
        float acc[19] = {0.f};
        const float* wr = a.ow1 + (size_t)o * 512;
        for (int c = 0; c < 512; ++c) {
            float wv = wr[c];
#pragma unroll
            for (int kk = 0; kk < 19; ++kk) acc[kk] += wv * pl[c * 19 + kk];
        }
        float sc = a.og1[o] * __frsqrt_rn(a.ov1[o] + 1e-5f);
        float sh = a.ob1[o] - a.om1[o] * sc;
#pragma unroll
        for (int kk = 0; kk < 19; ++kk) t1[o * 19 + kk] = fmaxf(acc[kk] * sc + sh, 0.f);
    }
    __syncthreads();
    {
        float acc[19] = {0.f};
        const float* wr = a.ow2 + (size_t)o * 256;
        for (int c = 0; c < 256; ++c) {
            float wv = wr[c];
#pragma unroll
            for (int kk = 0; kk < 19; ++kk) acc[kk] += wv * t1[c * 19 + kk];
        }
        float sc = a.og2[o] * __frsqrt_rn(a.ov2[o] + 1e-5f);
        float sh = a.ob2[o] - a.om2[o] * sc;
#pragma unroll
        for (int kk = 0; kk < 19; ++kk)
            a.kmat[((size_t)b * 256 + o) * 19 + kk] = fmaxf(acc[kk] * sc + sh, 0.f);
    }
    {
        float acc[19] = {0.f};
        const float* wr = a.dw + (size_t)o * 512;
        for (int c = 0; c < 512; ++c) {
            float wv = wr[c];
#pragma unroll
            for (int kk = 0; kk < 19; ++kk) acc[kk] += wv * pl[c * 19 + kk];
        }
        float sc = a.dg[o] * __frsqrt_rn(a.dv[o] + 1e-5f);
        float sh = a.db[o] - a.dm[o] * sc;
#pragma unroll
        for (int kk = 0; kk < 19; ++kk)
            a.vmat[((size_t)b * 19 + kk) * 256 + o] = fmaxf(acc[kk] * sc + sh, 0.f);
    }
}

// ---------------------------------------------------------------- attention: 2 threads/px, 128 px/block
// ctx written in gemm_up A-FRAGMENT order: per 64-px tile [s 8][pg 4][lane 64][8],
// value(tile,s,pg,l) = ctx[px = pg*16+(l&15)][k = s*32+(l>>4)*8].
struct AttnArgs { const float* q2f; const float* kmat; const float* vmat;
                  u16* ctxh; u16* ctxl; long long p_off; };
__global__ __launch_bounds__(256, 3) void attn_kernel(AttnArgs a) {
    __shared__ float kl[4864];        // [c][19]
    __shared__ float vl[4864];        // [kk][256]
    __shared__ float sp[128 * 21];    // partial sims / shared weights (stride 21: conflict-free)
    const int t = threadIdx.x;
    const int px = t & 127, hf = t >> 7;
    const size_t pl_ = (size_t)blockIdx.x * 128;       // pass-local pixel base
    const size_t gpx0 = (size_t)a.p_off + pl_;         // global pixel base (multiple of 128)
    const int b = (int)(gpx0 >> 14);
    for (int i = t; i < 4864; i += 256) { kl[i] = a.kmat[(size_t)b * 4864 + i];
                                          vl[i] = a.vmat[(size_t)b * 4864 + i]; }
    __syncthreads();
    const float* qrow = a.q2f + (pl_ + px) * 256 + hf * 128;
    float sim[19];
#pragma unroll
    for (int kk = 0; kk < 19; ++kk) sim[kk] = 0.f;
    for (int j = 0; j < 32; ++j) {
        float4 qv = reinterpret_cast<const float4*>(qrow)[j];
#pragma unroll
        for (int e = 0; e < 4; ++e) {
            float qf = (e == 0) ? qv.x : (e == 1) ? qv.y : (e == 2) ? qv.z : qv.w;
            int c = hf * 128 + j * 4 + e;
#pragma unroll
            for (int kk = 0; kk < 19; ++kk) sim[kk] += qf * kl[c * 19 + kk];
        }
    }
    if (hf == 1) {
#pragma unroll
        for (int kk = 0; kk < 19; ++kk) sp[px * 21 + kk] = sim[kk];
    }
    __syncthreads();
    if (hf == 0) {
        float mx = -1e30f;
#pragma unroll
        for (int kk = 0; kk < 19; ++kk) {
            sim[kk] = (sim[kk] + sp[px * 21 + kk]) * 0.0625f;
            mx = fmaxf(mx, sim[kk]);
        }
        float ssum = 0.f;
#pragma unroll
        for (int kk = 0; kk < 19; ++kk) { sim[kk] = __expf(sim[kk] - mx); ssum += sim[kk]; }
        const float inv = 1.f / ssum;
#pragma unroll
        for (int kk = 0; kk < 19; ++kk) sp[px * 21 + kk] = sim[kk] * inv;
    }
    __syncthreads();
    float wgt[19];
#pragma unroll
    for (int kk = 0; kk < 19; ++kk) wgt[kk] = sp[px * 21 + kk];
    // fragment-order ctx store for this half's 128 channels
    const int Pg = (int)(gpx0) + px;
    const int tile = Pg >> 6, r = Pg & 63;
    const int pgg = r >> 4, l15a = r & 15;
    u16* th = a.ctxh + (size_t)tile * 16384;
    u16* tl = a.ctxl + (size_t)tile * 16384;
#pragma unroll
    for (int j2 = 0; j2 < 16; ++j2) {
        const int j = hf * 16 + j2;            // channel octet: c = j*8 + e
        const int s = j >> 2, l4c = j & 3;
        U4 hh, ll;
#pragma unroll
        for (int e = 0; e < 8; ++e) {
            int c = j * 8 + e;
            float acc = 0.f;
#pragma unroll
            for (int kk = 0; kk < 19; ++kk) acc += wgt[kk] * vl[kk * 256 + c];
            split2(acc, hh.s[e], ll.s[e]);
        }
        const int off = (s * 4 + pgg) * 512 + (l4c * 16 + l15a) * 8;
        *reinterpret_cast<uint4*>(&th[off]) = hh.v;
        *reinterpret_cast<uint4*>(&tl[off]) = ll.v;
    }
}

// ---------------------------------------------------------------- FUSED gemm1+gemm2, 64-px blocks, 2 blocks/CU
// W1/W2 pre-packed lane-linear: every global load instruction is contiguous 1 KB.
struct F12Args {
    const float* Xf;
    const u16 *W1h, *W1l, *W2h, *W2l;   // packed
    const float *g1, *b1, *m1, *v1;
    const float *g2, *b2, *m2, *v2;
    float* q2f;     // pass-local [chunk_px][256] fp32
    int m_off;
};
__global__ __launch_bounds__(256, 2) void fused12_kernel(F12Args a) {
    __shared__ char LB[81920];
    u16* xs = (u16*)LB;               // 2 buf x 2 planes x [64][32] u16  (16384 B)
    u16* wb = (u16*)(LB + 16384);     // 2 buf x 2 planes x [256][32] u16 (65536 B)
    u16* q1 = (u16*)LB;               // phase2: 2 planes x 16 rows x 280 u16 (17920 B)
    float* tf = (float*)LB;           // epilogue: [16][260] f32 (16640 B), aliases q1

    const int t = threadIdx.x;
    const int l = t & 63, w = t >> 6;
    const int wr = w >> 1, wc = w & 1;
    const int l15 = l & 15, l4 = l >> 4;
    const int mloc = blockIdx.x * 64;
    const int mg = a.m_off + mloc;
    const int bb = mg >> 14, nb = mg & 16383;   // 64 | 16384 -> no batch straddle

    f32x4 acc1[2][8];
#pragma unroll
    for (int mi = 0; mi < 2; ++mi)
#pragma unroll
        for (int ni = 0; ni < 8; ++ni) acc1[mi][ni] = f32x4{0.f, 0.f, 0.f, 0.f};

    float fx[8];

    auto loadX = [&](int s) {
        const int px = t & 63, oct = t >> 6;     // 256 tasks: 64 px x 4 octs
        const float* src = a.Xf + (((size_t)bb * 512 + s * 32 + oct * 8) << 14) + nb + px;
#pragma unroll
        for (int e = 0; e < 8; ++e) fx[e] = src[(size_t)e << 14];
    };
    auto writeX = [&](int buf) {
        const int px = t & 63, oct = t >> 6;
        U4 ph, plo;
#pragma unroll
        for (int e = 0; e < 8; ++e) split2(fx[e], ph.s[e], plo.s[e]);
        int pos = buf * 4096 + px * 32 + ((oct ^ swz(px)) * 8);
        *reinterpret_cast<uint4*>(&xs[pos]) = ph.v;
        *reinterpret_cast<uint4*>(&xs[2048 + pos]) = plo.v;
    };
    auto dmaW1 = [&](int s, int buf) {
        // packed: contiguous 1 KB per instruction (base + l*16)
        const u16* bh = a.W1h + (size_t)s * 8192 + l * 8;
        const u16* bl2 = a.W1l + (size_t)s * 8192 + l * 8;
#pragma unroll
        for (int g = 0; g < 4; ++g) {
            const int rg = w * 4 + g;            // 16-row group
            gload16(bh + rg * 512, &wb[buf * 16384 + rg * 512]);
            gload16(bl2 + rg * 512, &wb[buf * 16384 + 8192 + rg * 512]);
        }
    };

    // ---------------- phase 1: K=512 in 16 steps of 32, single barrier/step
    loadX(0); dmaW1(0, 0);
    writeX(0);
    loadX(1);
    __syncthreads();
    int cur = 0;
    for (int s = 0; s < 16; ++s) {
        if (s < 15) dmaW1(s + 1, cur ^ 1);
        bf16x8 ah[2], am[2];
#pragma unroll
        for (int mi = 0; mi < 2; ++mi) {
            int ar = wr * 32 + mi * 16 + l15;
            int ap = cur * 4096 + ar * 32 + ((l4 ^ swz(ar)) * 8);
            ah[mi] = *reinterpret_cast<const bf16x8*>(&xs[ap]);
            am[mi] = *reinterpret_cast<const bf16x8*>(&xs[2048 + ap]);
        }
#pragma unroll
        for (int ni = 0; ni < 8; ++ni) {
            int br = wc * 128 + ni * 16 + l15;
            int bp = cur * 16384 + br * 32 + ((l4 ^ swz(br)) * 8);
            bf16x8 bh = *reinterpret_cast<const bf16x8*>(&wb[bp]);
            bf16x8 bl_ = *reinterpret_cast<const bf16x8*>(&wb[8192 + bp]);
#pragma unroll
            for (int mi = 0; mi < 2; ++mi) {
                acc1[mi][ni] = __builtin_amdgcn_mfma_f32_16x16x32_bf16(ah[mi], bh, acc1[mi][ni], 0, 0, 0);
                acc1[mi][ni] = __builtin_amdgcn_mfma_f32_16x16x32_bf16(ah[mi], bl_, acc1[mi][ni], 0, 0, 0);
                acc1[mi][ni] = __builtin_amdgcn_mfma_f32_16x16x32_bf16(am[mi], bh, acc1[mi][ni], 0, 0, 0);
            }
        }
        if (s < 15) {
            writeX(cur ^ 1);
            if (s < 14) loadX(s + 2);
        }
        __syncthreads();
        cur ^= 1;
    }

    // BN coefficients
    float scl1[8], shf1[8];
#pragma unroll
    for (int ni = 0; ni < 8; ++ni) {
        int o = wc * 128 + ni * 16 + l15;
        scl1[ni] = a.g1[o] * __frsqrt_rn(a.v1[o] + 1e-5f);
        shf1[ni] = a.b1[o] - a.m1[o] * scl1[ni];
    }
    float scl2[4], shf2[4];
#pragma unroll
    for (int ni = 0; ni < 4; ++ni) {
        int o = w * 64 + ni * 16 + l15;
        scl2[ni] = a.g2[o] * __frsqrt_rn(a.v2[o] + 1e-5f);
        shf2[ni] = a.b2[o] - a.m2[o] * scl2[ni];
    }

    // ---------------- phase 2: 4 chunks of 16 px (fully unrolled; acc1 indices compile-time)
#pragma unroll
    for (int pxq = 0; pxq < 4; ++pxq) {
        const int mi = pxq & 1;
        __syncthreads();
        if (wr == (pxq >> 1)) {
#pragma unroll
            for (int ni = 0; ni < 8; ++ni) {
                int o1 = wc * 128 + ni * 16 + l15;
                int base = (o1 >> 3) * 8 + (o1 & 7);
#pragma unroll
                for (int r = 0; r < 4; ++r) {
                    int px_l = l4 * 4 + r;
                    float y = fmaxf(acc1[mi][ni][r] * scl1[ni] + shf1[ni], 0.f);
                    u16 h, lo; split2(y, h, lo);
                    int pos = px_l * 280 + base;
                    q1[pos] = h;
                    q1[4480 + pos] = lo;
                }
            }
        }
        __syncthreads();

        f32x4 acc2[4];
#pragma unroll
        for (int ni = 0; ni < 4; ++ni) acc2[ni] = f32x4{0.f, 0.f, 0.f, 0.f};

#pragma unroll
        for (int s2 = 0; s2 < 8; ++s2) {       // W2 packed: contiguous 1 KB loads
            int ap = l15 * 280 + (s2 * 4 + l4) * 8;
            bf16x8 a2h = *reinterpret_cast<const bf16x8*>(&q1[ap]);
            bf16x8 a2m = *reinterpret_cast<const bf16x8*>(&q1[4480 + ap]);
            const size_t bo0 = (size_t)(w * 8 + s2) * 2048 + l * 8;
#pragma unroll
            for (int ni = 0; ni < 4; ++ni) {
                bf16x8 b2h = *reinterpret_cast<const bf16x8*>(&a.W2h[bo0 + ni * 512]);
                bf16x8 b2l = *reinterpret_cast<const bf16x8*>(&a.W2l[bo0 + ni * 512]);
                acc2[ni] = __builtin_amdgcn_mfma_f32_16x16x32_bf16(a2h, b2h, acc2[ni], 0, 0, 0);
                acc2[ni] = __builtin_amdgcn_mfma_f32_16x16x32_bf16(a2h, b2l, acc2[ni], 0, 0, 0);
                acc2[ni] = __builtin_amdgcn_mfma_f32_16x16x32_bf16(a2m, b2h, acc2[ni], 0, 0, 0);
            }
        }
        __syncthreads();

        // q2 epilogue -> tf -> coalesced float4 stores
#pragma unroll
        for (int ni = 0; ni < 4; ++ni) {
            int o2 = w * 64 + ni * 16 + l15;
#pragma unroll
            for (int r = 0; r < 4; ++r) {
                int px_l = l4 * 4 + r;
                tf[px_l * 260 + o2] = fmaxf(acc2[ni][r] * scl2[ni] + shf2[ni], 0.f);
            }
        }
        __syncthreads();
#pragma unroll
        for (int j = 0; j < 4; ++j) {
            int task = j * 256 + t;
            int row = task >> 6, c4 = task & 63;
            *reinterpret_cast<float4*>(&a.q2f[(size_t)(mloc + pxq * 16 + row) * 256 + c4 * 4]) =
                *reinterpret_cast<const float4*>(&tf[row * 260 + c4 * 4]);
        }
    }
}

// ---------------------------------------------------------------- gemm_up: packed ctx + packed uw -> out[b][o][n] fp32
// All main-loop loads lane-contiguous 1 KB; barrier-free; 4 waves/EU.
struct GUArgs {
    const u16 *Ah, *Al, *Wh, *Wl;     // packed
    const float *gg, *bbv, *mmv, *vvv;
    float* Yf;
};
__global__ __launch_bounds__(256, 4) void gemm_up_kernel(GUArgs a) {
    __shared__ float ldsf[128 * 68];          // epilogue only (34816 B)
    const int t = threadIdx.x;
    const int l = t & 63;
    const int w = t >> 6;
    const int wr = w >> 1, wc = w & 1;
    const int l15 = l & 15, l4 = l >> 4;
    const int id = blockIdx.y * 4 + blockIdx.x;
    const int wid = (id & 7) * 1024 + (id >> 3);  // bijective XCD chunking (nwg=8192)
    const int o0 = (wid & 3) * 128;
    const int m  = (wid >> 2) * 64;
    const int bb = m >> 14;
    const int nb = m & 16383;

    f32x4 acc[2][4];
#pragma unroll
    for (int mi = 0; mi < 2; ++mi)
#pragma unroll
        for (int ni = 0; ni < 4; ++ni) acc[mi][ni] = f32x4{0.f, 0.f, 0.f, 0.f};

    // packed bases: A tile [s][pg][lane][8]; W [(o4*2+wc)*8+s][ni][lane][8]
    const size_t aoff0 = (size_t)(wid >> 2) * 16384 + (size_t)(wr * 2) * 512 + l * 8;
    const size_t woff0 = (size_t)(((wid & 3) * 2 + wc) * 8) * 2048 + l * 8;

#pragma unroll 2
    for (int s = 0; s < 8; ++s) {             // K=256 in 8 steps of 32, barrier-free
        const size_t as = aoff0 + (size_t)s * 2048;
        const size_t wso = woff0 + (size_t)s * 2048;
        bf16x8 ah[2], al[2], bh[4], bl[4];
#pragma unroll
        for (int mi = 0; mi < 2; ++mi) {
            ah[mi] = *reinterpret_cast<const bf16x8*>(a.Ah + as + mi * 512);
            al[mi] = *reinterpret_cast<const bf16x8*>(a.Al + as + mi * 512);
        }
#pragma unroll
        for (int ni = 0; ni < 4; ++ni) {
            bh[ni] = *reinterpret_cast<const bf16x8*>(a.Wh + wso + ni * 512);
            bl[ni] = *reinterpret_cast<const bf16x8*>(a.Wl + wso + ni * 512);
        }
#pragma unroll
        for (int mi = 0; mi < 2; ++mi)
#pragma unroll
            for (int ni = 0; ni < 4; ++ni) {
                acc[mi][ni] = __builtin_amdgcn_mfma_f32_16x16x32_bf16(ah[mi], bh[ni], acc[mi][ni], 0, 0, 0);
                acc[mi][ni] = __builtin_amdgcn_mfma_f32_16x16x32_bf16(ah[mi], bl[ni], acc[mi][ni], 0, 0, 0);
                acc[mi][ni] = __builtin_amdgcn_mfma_f32_16x16x32_bf16(al[mi], bh[ni], acc[mi][ni], 0, 0, 0);
            }
    }

    float scl[4], shf[4];
#pragma unroll
    for (int ni = 0; ni < 4; ++ni) {
        int o = o0 + wc * 64 + ni * 16 + l15;
        scl[ni] = a.gg[o] * __frsqrt_rn(a.vvv[o] + 1e-5f);
        shf[ni] = a.bbv[o] - a.mmv[o] * scl[ni];
    }

    // epilogue: transpose via LDS [128 o][68 n] f32 -> out[b][o][16384] coalesced
#pragma unroll
    for (int ni = 0; ni < 4; ++ni) {
        int o_l = wc * 64 + ni * 16 + l15;
#pragma unroll
        for (int mi = 0; mi < 2; ++mi)
#pragma unroll
            for (int r = 0; r < 4; ++r) {
                int n_l = wr * 32 + mi * 16 + l4 * 4 + r;
                float y = fmaxf(acc[mi][ni][r] * scl[ni] + shf[ni], 0.f);
                ldsf[o_l * 68 + n_l] = y;
            }
    }
    __syncthreads();
#pragma unroll
    for (int j = 0; j < 8; ++j) {
        int idx = j * 256 + t;
        int row = idx >> 4, c4 = (idx & 15) * 4;
        *reinterpret_cast<float4*>(&a.Yf[((size_t)bb << 23) + (size_t)(o0 + row) * 16384 + nb + c4]) =
            *reinterpret_cast<const float4*>(&ldsf[row * 68 + c4]);
    }
}

// ---------------------------------------------------------------- launch
extern "C" void kernel_launch(void* const* d_in, const int* in_sizes, int n_in,
                              void* d_out, int out_size, void* d_ws, size_t ws_size,
                              hipStream_t stream) {
    const float* x     = (const float*)d_in[0];
    const float* proxy = (const float*)d_in[1];
    const float* pw1 = (const float*)d_in[2];
    const float* pg1 = (const float*)d_in[3];
    const float* pb1 = (const float*)d_in[4];
    const float* pm1 = (const float*)d_in[5];
    const float* pv1 = (const float*)d_in[6];
    const float* pw2 = (const float*)d_in[7];
    const float* pg2 = (const float*)d_in[8];
    const float* pb2 = (const float*)d_in[9];
    const float* pm2 = (const float*)d_in[10];
    const float* pv2 = (const float*)d_in[11];
    const float* ow1 = (const float*)d_in[12];
    const float* og1 = (const float*)d_in[13];
    const float* ob1 = (const float*)d_in[14];
    const float* om1 = (const float*)d_in[15];
    const float* ov1 = (const float*)d_in[16];
    const float* ow2 = (const float*)d_in[17];
    const float* og2 = (const float*)d_in[18];
    const float* ob2 = (const float*)d_in[19];
    const float* om2 = (const float*)d_in[20];
    const float* ov2 = (const float*)d_in[21];
    const float* dw  = (const float*)d_in[22];
    const float* dg  = (const float*)d_in[23];
    const float* db  = (const float*)d_in[24];
    const float* dm  = (const float*)d_in[25];
    const float* dv  = (const float*)d_in[26];
    const float* uw  = (const float*)d_in[27];
    const float* ug  = (const float*)d_in[28];
    const float* ub  = (const float*)d_in[29];
    const float* um  = (const float*)d_in[30];
    const float* uv  = (const float*)d_in[31];

    char* ws = (char*)d_ws;
    u16* w1ph = (u16*)(ws + 0);                  // 262144 B (packed)
    u16* w1pl = (u16*)(ws + 262144);
    u16* w2ph = (u16*)(ws + 524288);             // 131072 B (packed)
    u16* w2pl = (u16*)(ws + 655360);
    u16* wuph = (u16*)(ws + 786432);             // 262144 B (packed)
    u16* wupl = (u16*)(ws + 1048576);
    float* kmat = (float*)(ws + 1310720);        // 155648 B
    float* vmat = (float*)(ws + 1466368);        // 155648 B -> ends 1622016
    u16* ctxh = (u16*)(ws + 2097152);            // 67108864 B (fragment-order)
    u16* ctxl = (u16*)(ws + 69206016);           // 67108864 B -> ends 136314880
    float* q2f = (float*)(ws + 136314880ull);    // 134217728/passes B, [chunk][256] fp32

    int passes = 1;
    while (passes < 16 && 136314880ull + 134217728ull / (size_t)passes > ws_size) passes <<= 1;

    pack_w1_kernel<<<64, 256, 0, stream>>>(pw1, w1ph, w1pl);
    pack_w2_kernel<<<32, 256, 0, stream>>>(pw2, w2ph, w2pl);
    pack_wu_kernel<<<64, 256, 0, stream>>>(uw,  wuph, wupl);

    KVArgs ka{proxy, ow1, og1, ob1, om1, ov1, ow2, og2, ob2, om2, ov2,
              dw, dg, db, dm, dv, kmat, vmat};
    kv_kernel<<<8, 256, 0, stream>>>(ka);

    const int mpix = 131072 / passes;            // pixels per pass
    for (int p = 0; p < passes; ++p) {
        const int m_off = p * mpix;
        F12Args fa{x, w1ph, w1pl, w2ph, w2pl,
                   pg1, pb1, pm1, pv1, pg2, pb2, pm2, pv2, q2f, m_off};
        fused12_kernel<<<mpix / 64, 256, 0, stream>>>(fa);
        AttnArgs aa{q2f, kmat, vmat, ctxh, ctxl, (long long)m_off};
        attn_kernel<<<mpix / 128, 256, 0, stream>>>(aa);
    }

    // gemm_up: packed ctx -> out[b][o][n] fp32
    GUArgs ga{ctxh, ctxl, wuph, wupl, ug, ub, um, uv, (float*)d_out};
    gemm_up_kernel<<<dim3(4, 2048), 256, 0, stream>>>(ga);
}